// Round 7
// baseline (666.715 us; speedup 1.0000x reference)
//
#include <hip/hip_runtime.h>
#include <cstdint>
#include <cstddef>
#include <math.h>

typedef __attribute__((ext_vector_type(8))) short short8;
typedef __attribute__((ext_vector_type(4))) float floatx4;
typedef unsigned short ushort_t;

__device__ __forceinline__ ushort_t f2bf(float x) {
    union { float f; unsigned u; } v; v.f = x;
    unsigned r = v.u + 0x7FFF + ((v.u >> 16) & 1);
    return (ushort_t)(r >> 16);
}
__device__ __forceinline__ float bf2f(ushort_t h) {
    union { unsigned u; float f; } v; v.u = ((unsigned)h) << 16; return v.f;
}
__device__ __forceinline__ void split2(float v, ushort_t& h, ushort_t& l) {
    h = f2bf(v);
    l = f2bf(v - bf2f(h));
}

#define MFMA(a, b, c) __builtin_amdgcn_mfma_f32_16x16x32_bf16((a), (b), (c), 0, 0, 0)

__device__ __forceinline__ void gload_lds16(const void* g, void* l) {
    __builtin_amdgcn_global_load_lds(
        (const __attribute__((address_space(1))) unsigned*)g,
        (__attribute__((address_space(3))) unsigned*)l, 16, 0, 0);
}

// ---------------------------------------------------------------------
// prep_all: all weight hi/lo splits + Wm transpose + BN fold, one launch.
// ---------------------------------------------------------------------
__global__ void prep_all_kernel(
    const float* __restrict__ Wq, const float* __restrict__ Ws,
    const float* __restrict__ Wg, const float* __restrict__ Wfi,
    const float* __restrict__ Wm,
    const float* bq, const float* bs,
    const float* bg, const float* gg, const float* gb, const float* gm, const float* gv,
    const float* bfi, const float* fg, const float* fb, const float* fm, const float* fv,
    const float* bm, const float* mg, const float* mb, const float* mm, const float* mv,
    ushort_t* Wq_h, ushort_t* Wq_l, ushort_t* Ws_h, ushort_t* Ws_l,
    ushort_t* Wg_h, ushort_t* Wg_l, ushort_t* Wfi_h, ushort_t* Wfi_l,
    ushort_t* wm_h, ushort_t* wm_l, float* scsh)
{
    int bid = blockIdx.x, t = threadIdx.x;
    if (bid < 256) {
        int i = bid * 256 + t; ushort_t h, l; split2(Wq[i], h, l); Wq_h[i] = h; Wq_l[i] = l;
    } else if (bid < 512) {
        int i = (bid - 256) * 256 + t; ushort_t h, l; split2(Ws[i], h, l); Ws_h[i] = h; Ws_l[i] = l;
    } else if (bid < 768) {
        int i = (bid - 512) * 256 + t; ushort_t h, l; split2(Wg[i], h, l); Wg_h[i] = h; Wg_l[i] = l;
    } else if (bid < 1280) {
        int i = (bid - 768) * 256 + t; ushort_t h, l; split2(Wfi[i], h, l); Wfi_h[i] = h; Wfi_l[i] = l;
    } else if (bid < 1856) {
        int i = (bid - 1280) * 256 + t;  // [tap][m][c] flattened
        int c = i & 255, m = (i >> 8) & 63, tap = i >> 14;
        ushort_t h, l; split2(Wm[((size_t)m * 256 + c) * 9 + tap], h, l);
        wm_h[i] = h; wm_l[i] = l;
    } else {
        if (t < 256) {
            scsh[t] = 1.f;        scsh[256 + t] = bq[t];
            scsh[512 + t] = 1.f;  scsh[768 + t] = bs[t];
            float s = gg[t] * rsqrtf(gv[t] + 1e-5f);
            scsh[1024 + t] = s;   scsh[1280 + t] = gb[t] + s * (bg[t] - gm[t]);
            float s2 = fg[t] * rsqrtf(fv[t] + 1e-5f);
            scsh[1536 + t] = s2;  scsh[1792 + t] = fb[t] + s2 * (bfi[t] - fm[t]);
            if (t < 64) {
                float s3 = mg[t] * rsqrtf(mv[t] + 1e-5f);
                scsh[2048 + t] = s3; scsh[2112 + t] = mb[t] + s3 * (bm[t] - mm[t]);
            }
        }
    }
}

// halo-only zero of gxT (128 halo rows per batch, hi+lo)
__global__ void halo_zero_kernel(ushort_t* __restrict__ gxh, ushort_t* __restrict__ gxl) {
    int i = blockIdx.x * 256 + threadIdx.x;   // 0..4095
    int b = i >> 7, k = i & 127;
    int r;
    if (k < 33) r = k;
    else if (k < 66) r = 32 * 33 + (k - 33);
    else { int k2 = k - 66; r = ((k2 >> 1) + 1) * 33 + ((k2 & 1) ? 32 : 0); }
    uint4* ph = (uint4*)(gxh + ((size_t)b * 1089 + r) * 256);
    uint4* pl = (uint4*)(gxl + ((size_t)b * 1089 + r) * 256);
    uint4 z = make_uint4(0, 0, 0, 0);
#pragma unroll
    for (int s = 0; s < 32; s++) { ph[s] = z; pl[s] = z; }
}

// fp32 [B][256][Nsrc] -> bf16 hi/lo [B][Npad][256]
__global__ __launch_bounds__(256) void transpose_in_kernel(
    const float* __restrict__ in, ushort_t* __restrict__ oh, ushort_t* __restrict__ ol,
    int Nsrc, int Npad)
{
    int b = blockIdx.z;
    const float* ib = in + (size_t)b * 256 * Nsrc;
    ushort_t* obh = oh + (size_t)b * Npad * 256;
    ushort_t* obl = ol + (size_t)b * Npad * 256;
    __shared__ float tile[32][33];
    int n0 = blockIdx.x * 32, c0 = blockIdx.y * 32;
    int tx = threadIdx.x & 31, ty = threadIdx.x >> 5;
#pragma unroll
    for (int r = 0; r < 4; r++) {
        int c = c0 + ty + r * 8, n = n0 + tx;
        tile[ty + r * 8][tx] = (n < Nsrc) ? ib[(size_t)c * Nsrc + n] : 0.f;
    }
    __syncthreads();
#pragma unroll
    for (int r = 0; r < 4; r++) {
        int n = n0 + ty + r * 8, c = c0 + tx;
        if (n < Nsrc) {
            ushort_t h, l; split2(tile[tx][ty + r * 8], h, l);
            obh[(size_t)n * 256 + c] = h;
            obl[(size_t)n * 256 + c] = l;
        }
    }
}

// ---------------------------------------------------------------------
// dual conv1x1: FUSED halves (low traffic — X staged ONCE for both convs)
// + 16-row tiles (16 KB LDS -> high occupancy). grid (B, NpadIn/16).
// Combines r4's traffic profile with r6's block concurrency.
// ---------------------------------------------------------------------
__global__ __launch_bounds__(256, 4) void dualconv_mfma_kernel(
    const ushort_t* __restrict__ Xh, const ushort_t* __restrict__ Xl,
    const ushort_t* __restrict__ W1h, const ushort_t* __restrict__ W1l,
    const ushort_t* __restrict__ W2h, const ushort_t* __restrict__ W2l,
    const float* __restrict__ sc1, const float* __restrict__ sh1,
    const float* __restrict__ sc2, const float* __restrict__ sh2,
    int relu1, int relu2,
    ushort_t* __restrict__ O1h, ushort_t* __restrict__ O1l,
    ushort_t* __restrict__ O2h, ushort_t* __restrict__ O2l,
    ushort_t* __restrict__ O2ch, ushort_t* __restrict__ O2cl, int cpitch,
    int K, int Nvalid, int NpadIn, int NpadOut)
{
    __shared__ ushort_t Bs[8192];   // 16 KB: hi rows @byte 0, lo rows @byte 8192
    int b = blockIdx.x;
    int n0 = blockIdx.y * 16;
    const ushort_t* Xbh = Xh + (size_t)b * NpadIn * K;
    const ushort_t* Xbl = Xl + (size_t)b * NpadIn * K;
    int tid = threadIdx.x, w = tid >> 6, l = tid & 63, lc = l & 15, q = l >> 4;
    int m0 = w * 64;

    // ---- stage 16-row B tile (swizzle: in-row byte ^= (row&7)<<4, via src) ----
#pragma unroll
    for (int r = 0; r < 4; r++) {
        int d = r * 4096 + tid * 16;       // linear byte in 16KB region
        int seg = d >> 13;                  // 0 = hi, 1 = lo
        int dr = d & 8191;
        int row = dr >> 9;                  // 0..15
        int inrow = (dr & 511) ^ ((row & 7) << 4);
        int srow = n0 + row; if (srow > NpadIn - 1) srow = NpadIn - 1;
        const ushort_t* src = (seg ? Xbl : Xbh) + (size_t)srow * K + (inrow >> 1);
        gload_lds16(src, (char*)Bs + d);
    }
    __syncthreads();

#define DC_LOADA(K0, AH, AL) do { \
    _Pragma("unroll") \
    for (int mt_ = 0; mt_ < 4; mt_++) { \
        size_t off_ = (size_t)(m0 + mt_ * 16 + lc) * K + (K0) + q * 8; \
        AH[mt_] = *(const short8*)(Wh + off_); \
        AL[mt_] = *(const short8*)(Wl + off_); \
    } \
} while (0)
#define DC_LDSB(K0, BH, BL) do { \
    int koff_ = (((K0) + q * 8) * 2) ^ ((lc & 7) << 4); \
    BH = *(const short8*)((const char*)Bs + lc * 512 + koff_); \
    BL = *(const short8*)((const char*)Bs + 8192 + lc * 512 + koff_); \
} while (0)
#define DC_MFMA(AH, AL, BH, BL) do { \
    _Pragma("unroll") \
    for (int mt_ = 0; mt_ < 4; mt_++) { \
        acc[mt_] = MFMA(AH[mt_], BH, acc[mt_]); \
        acc[mt_] = MFMA(AH[mt_], BL, acc[mt_]); \
        acc[mt_] = MFMA(AL[mt_], BH, acc[mt_]); \
    } \
} while (0)

    for (int half = 0; half < 2; half++) {
        const ushort_t* Wh = half ? W2h : W1h;
        const ushort_t* Wl = half ? W2l : W1l;
        const float* sc = half ? sc2 : sc1;
        const float* sh = half ? sh2 : sh1;
        int relu = half ? relu2 : relu1;
        ushort_t* Obh = (half ? O2h : O1h) + (size_t)b * NpadOut * 256;
        ushort_t* Obl = (half ? O2l : O1l) + (size_t)b * NpadOut * 256;

        floatx4 acc[4];
#pragma unroll
        for (int i = 0; i < 4; i++) acc[i] = (floatx4){0.f, 0.f, 0.f, 0.f};

        short8 ah0[4], al0[4], ah1[4], al1[4], bh, bl;
        DC_LOADA(0, ah0, al0);
        for (int k0 = 0; k0 < K; k0 += 64) {
            DC_LOADA(k0 + 32, ah1, al1);
            DC_LDSB(k0, bh, bl);
            DC_MFMA(ah0, al0, bh, bl);
            if (k0 + 64 < K) DC_LOADA(k0 + 64, ah0, al0);
            DC_LDSB(k0 + 32, bh, bl);
            DC_MFMA(ah1, al1, bh, bl);
        }

        int n = n0 + lc;
        if (n < Nvalid) {
#pragma unroll
            for (int mt = 0; mt < 4; mt++) {
                int mb = m0 + mt * 16 + q * 4;
                float s0 = sc[mb], s1 = sc[mb + 1], s2 = sc[mb + 2], s3 = sc[mb + 3];
                float h0 = sh[mb], h1 = sh[mb + 1], h2 = sh[mb + 2], h3 = sh[mb + 3];
                float v0 = acc[mt][0] * s0 + h0;
                float v1 = acc[mt][1] * s1 + h1;
                float v2 = acc[mt][2] * s2 + h2;
                float v3 = acc[mt][3] * s3 + h3;
                if (relu) { v0 = fmaxf(v0, 0.f); v1 = fmaxf(v1, 0.f); v2 = fmaxf(v2, 0.f); v3 = fmaxf(v3, 0.f); }
                ushort_t e0, f0, e1, f1, e2, f2, e3, f3;
                split2(v0, e0, f0); split2(v1, e1, f1); split2(v2, e2, f2); split2(v3, e3, f3);
                *(ushort4*)(Obh + (size_t)n * 256 + mb) = make_ushort4(e0, e1, e2, e3);
                *(ushort4*)(Obl + (size_t)n * 256 + mb) = make_ushort4(f0, f1, f2, f3);
                if (half && O2ch) {
                    O2ch[((size_t)b * 256 + mb + 0) * cpitch + n] = e0;
                    O2ch[((size_t)b * 256 + mb + 1) * cpitch + n] = e1;
                    O2ch[((size_t)b * 256 + mb + 2) * cpitch + n] = e2;
                    O2ch[((size_t)b * 256 + mb + 3) * cpitch + n] = e3;
                    O2cl[((size_t)b * 256 + mb + 0) * cpitch + n] = f0;
                    O2cl[((size_t)b * 256 + mb + 1) * cpitch + n] = f1;
                    O2cl[((size_t)b * 256 + mb + 2) * cpitch + n] = f2;
                    O2cl[((size_t)b * 256 + mb + 3) * cpitch + n] = f3;
                }
            }
        }
    }
#undef DC_LOADA
#undef DC_LDSB
#undef DC_MFMA
}

// ---------------------------------------------------------------------
// attention via MFMA: sim GEMM -> fp32 softmax -> emb GEMM. grid (B, 16).
// ---------------------------------------------------------------------
__global__ __launch_bounds__(256) void attn_mfma_kernel(
    const ushort_t* __restrict__ xth, const ushort_t* __restrict__ xtl,
    const ushort_t* __restrict__ zth, const ushort_t* __restrict__ ztl,
    const ushort_t* __restrict__ zgh, const ushort_t* __restrict__ zgl,
    ushort_t* __restrict__ eh, ushort_t* __restrict__ el)
{
    __shared__ float S[64][68];
    __shared__ ushort_t awh[64][72], awl[64][72];
    __shared__ float T[4][16][20];
    int b = blockIdx.x, n0 = blockIdx.y * 64;
    int tid = threadIdx.x, w = tid >> 6, l = tid & 63, lc = l & 15, q = l >> 4;
    const ushort_t* xhb = xth + (size_t)b * 992 * 256;
    const ushort_t* xlb = xtl + (size_t)b * 992 * 256;
    const ushort_t* zhb = zth + (size_t)b * 64 * 256;
    const ushort_t* zlb = ztl + (size_t)b * 64 * 256;
    const ushort_t* ghb = zgh + (size_t)b * 256 * 64;
    const ushort_t* glb = zgl + (size_t)b * 256 * 64;

    int rowg = n0 + w * 16 + lc;
#pragma unroll
    for (int ct = 0; ct < 4; ct++) {
        floatx4 acc = (floatx4){0.f, 0.f, 0.f, 0.f};
        for (int k0 = 0; k0 < 256; k0 += 32) {
            short8 ah = *(const short8*)(xhb + (size_t)rowg * 256 + k0 + q * 8);
            short8 al = *(const short8*)(xlb + (size_t)rowg * 256 + k0 + q * 8);
            short8 bh = *(const short8*)(zhb + (size_t)(ct * 16 + lc) * 256 + k0 + q * 8);
            short8 bl = *(const short8*)(zlb + (size_t)(ct * 16 + lc) * 256 + k0 + q * 8);
            acc = MFMA(ah, bh, acc);
            acc = MFMA(ah, bl, acc);
            acc = MFMA(al, bh, acc);
        }
#pragma unroll
        for (int r = 0; r < 4; r++) S[w * 16 + q * 4 + r][ct * 16 + lc] = acc[r];
    }
    __syncthreads();
    if (tid < 64) {
        float mx = -INFINITY;
        for (int m = 0; m < 49; m++) mx = fmaxf(mx, S[tid][m]);
        float sum = 0.f;
        for (int m = 0; m < 49; m++) { float e = __expf(S[tid][m] - mx); S[tid][m] = e; sum += e; }
        float inv = 1.f / sum;
        for (int m = 0; m < 64; m++) {
            float vv = (m < 49) ? S[tid][m] * inv : 0.f;
            ushort_t hh, ll; split2(vv, hh, ll);
            awh[tid][m] = hh; awl[tid][m] = ll;
        }
    }
    __syncthreads();
    int nw = l >> 2, cg = l & 3;
#pragma unroll
    for (int ct = 0; ct < 16; ct++) {
        floatx4 acc = (floatx4){0.f, 0.f, 0.f, 0.f};
#pragma unroll
        for (int k0 = 0; k0 < 64; k0 += 32) {
            short8 ah = *(const short8*)(&awh[w * 16 + lc][k0 + q * 8]);
            short8 al = *(const short8*)(&awl[w * 16 + lc][k0 + q * 8]);
            short8 bh = *(const short8*)(ghb + (size_t)(ct * 16 + lc) * 64 + k0 + q * 8);
            short8 bl = *(const short8*)(glb + (size_t)(ct * 16 + lc) * 64 + k0 + q * 8);
            acc = MFMA(ah, bh, acc);
            acc = MFMA(ah, bl, acc);
            acc = MFMA(al, bh, acc);
        }
#pragma unroll
        for (int r = 0; r < 4; r++) T[w][q * 4 + r][lc] = acc[r];
        float4 vv = *(const float4*)&T[w][nw][cg * 4];
        int n = n0 + w * 16 + nw;
        if (n < 961) {
            ushort_t h0, l0, h1, l1, h2, l2_, h3, l3;
            split2(vv.x, h0, l0); split2(vv.y, h1, l1);
            split2(vv.z, h2, l2_); split2(vv.w, h3, l3);
            size_t off = ((size_t)b * 992 + n) * 256 + ct * 16 + cg * 4;
            *(ushort4*)(eh + off) = make_ushort4(h0, h1, h2, h3);
            *(ushort4*)(el + off) = make_ushort4(l0, l1, l2_, l3);
        }
    }
}

// ---------------------------------------------------------------------
// fi conv (K=512 concat(emb, xf_g), hi/lo), two-phase 16 KB LDS staging,
// 16-row tiles for occupancy. grid (B, 62).
// ---------------------------------------------------------------------
__global__ __launch_bounds__(256, 4) void fi_mfma_kernel(
    const ushort_t* __restrict__ Eh, const ushort_t* __restrict__ El,
    const ushort_t* __restrict__ Gh, const ushort_t* __restrict__ Gl,
    const ushort_t* __restrict__ Wh, const ushort_t* __restrict__ Wl,
    const float* __restrict__ sc, const float* __restrict__ sh,
    ushort_t* __restrict__ gxh, ushort_t* __restrict__ gxl,
    ushort_t* __restrict__ gat_nf)
{
    __shared__ ushort_t Bs[8192];  // 16KB: hi@0, lo@byte 8192
    int b = blockIdx.x;
    const ushort_t* Ebh = Eh + (size_t)b * 992 * 256;
    const ushort_t* Ebl = El + (size_t)b * 992 * 256;
    const ushort_t* Gbh = Gh + (size_t)b * 992 * 256;
    const ushort_t* Gbl = Gl + (size_t)b * 992 * 256;
    ushort_t* gxhb = gxh + (size_t)b * 1089 * 256;
    ushort_t* gxlb = gxl + (size_t)b * 1089 * 256;
    ushort_t* gn = gat_nf + (size_t)b * 256 * 992;
    int tid = threadIdx.x, w = tid >> 6, l = tid & 63, lc = l & 15, q = l >> 4;
    int m0 = w * 64, nb0 = blockIdx.y * 16;

    floatx4 acc[4];
#pragma unroll
    for (int i = 0; i < 4; i++) acc[i] = (floatx4){0.f, 0.f, 0.f, 0.f};

#define FI_LOADA(K0, AH, AL) do { \
    _Pragma("unroll") \
    for (int mt_ = 0; mt_ < 4; mt_++) { \
        size_t off_ = (size_t)(m0 + mt_ * 16 + lc) * 512 + (K0) + q * 8; \
        AH[mt_] = *(const short8*)(Wh + off_); \
        AL[mt_] = *(const short8*)(Wl + off_); \
    } \
} while (0)
#define FI_LDSB(K0, BH, BL) do { \
    int koff_ = (((K0) + q * 8) * 2) ^ ((lc & 7) << 4); \
    BH = *(const short8*)((const char*)Bs + lc * 512 + koff_); \
    BL = *(const short8*)((const char*)Bs + 8192 + lc * 512 + koff_); \
} while (0)
#define FI_MFMA(AH, AL, BH, BL) do { \
    _Pragma("unroll") \
    for (int mt_ = 0; mt_ < 4; mt_++) { \
        acc[mt_] = MFMA(AH[mt_], BH, acc[mt_]); \
        acc[mt_] = MFMA(AH[mt_], BL, acc[mt_]); \
        acc[mt_] = MFMA(AL[mt_], BH, acc[mt_]); \
    } \
} while (0)

    for (int p = 0; p < 2; p++) {
        const ushort_t* srcH = p ? Gbh : Ebh;
        const ushort_t* srcL = p ? Gbl : Ebl;
        if (p) __syncthreads();            // all waves done reading phase-0 LDS
#pragma unroll
        for (int r = 0; r < 4; r++) {
            int d = r * 4096 + tid * 16;
            int seg = d >> 13;
            int dr = d & 8191;
            int row = dr >> 9;
            int inrow = (dr & 511) ^ ((row & 7) << 4);
            int srow = nb0 + row; if (srow > 991) srow = 991;
            const ushort_t* src = (seg ? srcL : srcH) + (size_t)srow * 256 + (inrow >> 1);
            gload_lds16(src, (char*)Bs + d);
        }
        __syncthreads();                   // staging complete (vmcnt drained)

        int pb = p * 256;
        short8 ah0[4], al0[4], ah1[4], al1[4], bh, bl;
        FI_LOADA(pb, ah0, al0);
        for (int kk = 0; kk < 256; kk += 64) {
            FI_LOADA(pb + kk + 32, ah1, al1);
            FI_LDSB(kk, bh, bl);
            FI_MFMA(ah0, al0, bh, bl);
            if (kk + 64 < 256) FI_LOADA(pb + kk + 64, ah0, al0);
            FI_LDSB(kk + 32, bh, bl);
            FI_MFMA(ah1, al1, bh, bl);
        }
    }
#undef FI_LOADA
#undef FI_LDSB
#undef FI_MFMA

    int n = nb0 + lc;
    if (n < 961) {
        int hh = n / 31, ww2 = n - hh * 31;
        int row = (hh + 1) * 33 + (ww2 + 1);
#pragma unroll
        for (int mt = 0; mt < 4; mt++) {
            int mb = m0 + mt * 16 + q * 4;
            float s0 = sc[mb], s1 = sc[mb + 1], s2 = sc[mb + 2], s3 = sc[mb + 3];
            float h0 = sh[mb], h1 = sh[mb + 1], h2 = sh[mb + 2], h3 = sh[mb + 3];
            float v0 = fmaxf(acc[mt][0] * s0 + h0, 0.f);
            float v1 = fmaxf(acc[mt][1] * s1 + h1, 0.f);
            float v2 = fmaxf(acc[mt][2] * s2 + h2, 0.f);
            float v3 = fmaxf(acc[mt][3] * s3 + h3, 0.f);
            ushort_t a0, b0, a1, b1, a2, b2, a3, b3;
            split2(v0, a0, b0); split2(v1, a1, b1); split2(v2, a2, b2); split2(v3, a3, b3);
            *(ushort4*)(gxhb + (size_t)row * 256 + mb) = make_ushort4(a0, a1, a2, a3);
            *(ushort4*)(gxlb + (size_t)row * 256 + mb) = make_ushort4(b0, b1, b2, b3);
            gn[(size_t)(mb + 0) * 992 + n] = a0;
            gn[(size_t)(mb + 1) * 992 + n] = a1;
            gn[(size_t)(mb + 2) * 992 + n] = a2;
            gn[(size_t)(mb + 3) * 992 + n] = a3;
        }
    }
}

// ---------------------------------------------------------------------
// conv3x3 split-K: block = 4 waves over ONE 64m x 64j tile, 72 (tap,k0)
// steps split 18/wave (k0-major, tap-fast), 1-deep register double-buffer,
// partials reduced in LDS in two 32j phases. grid (B, 16) batch-major.
// ---------------------------------------------------------------------
__global__ __launch_bounds__(256, 2) void conv3x3_mfma_kernel(
    const ushort_t* __restrict__ gxh, const ushort_t* __restrict__ gxl,
    const ushort_t* __restrict__ wmh, const ushort_t* __restrict__ wml,
    const float* __restrict__ sc, const float* __restrict__ sh,
    const float* __restrict__ prelu_a,
    ushort_t* __restrict__ eh, ushort_t* __restrict__ el)
{
    __shared__ float Sp[4][2048];   // 4 waves x (64m x 32j) partials, 32 KB
    int b = blockIdx.x;
    const ushort_t* gxhb = gxh + (size_t)b * 1089 * 256;
    const ushort_t* gxlb = gxl + (size_t)b * 1089 * 256;
    ushort_t* ebh = eh + (size_t)b * 1024 * 64;
    ushort_t* ebl = el + (size_t)b * 1024 * 64;
    int tid = threadIdx.x, w = tid >> 6, l = tid & 63, lc = l & 15, q = l >> 4;
    int j0 = blockIdx.y * 64;

    int base[4];
#pragma unroll
    for (int jt = 0; jt < 4; jt++) {
        int j = j0 + jt * 16 + lc; if (j > 960) j = 960;
        int hh = j / 31, ww2 = j - hh * 31;
        base[jt] = (hh + 1) * 33 + (ww2 + 1);
    }

    floatx4 acc[4][4];
#pragma unroll
    for (int i = 0; i < 4; i++)
#pragma unroll
        for (int j = 0; j < 4; j++) acc[i][j] = (floatx4){0.f, 0.f, 0.f, 0.f};

#define C3_LOAD(SL, AH, AL, BH, BL) do { \
    int sl_ = (SL); \
    int tap_ = (sl_ >= 9) ? sl_ - 9 : sl_; \
    int k0_ = (w * 2 + ((sl_ >= 9) ? 1 : 0)) * 32; \
    int doff_ = (tap_ / 3 - 1) * 33 + (tap_ % 3 - 1); \
    const ushort_t* wth_ = wmh + tap_ * 16384; \
    const ushort_t* wtl_ = wml + tap_ * 16384; \
    _Pragma("unroll") \
    for (int mt_ = 0; mt_ < 4; mt_++) { \
        size_t off_ = (size_t)(mt_ * 16 + lc) * 256 + k0_ + q * 8; \
        AH[mt_] = *(const short8*)(wth_ + off_); \
        AL[mt_] = *(const short8*)(wtl_ + off_); \
    } \
    _Pragma("unroll") \
    for (int jt_ = 0; jt_ < 4; jt_++) { \
        size_t off_ = (size_t)(base[jt_] + doff_) * 256 + k0_ + q * 8; \
        BH[jt_] = *(const short8*)(gxhb + off_); \
        BL[jt_] = *(const short8*)(gxlb + off_); \
    } \
} while (0)
#define C3_MFMA(AH, AL, BH, BL) do { \
    _Pragma("unroll") \
    for (int mt_ = 0; mt_ < 4; mt_++) \
    _Pragma("unroll") \
    for (int jt_ = 0; jt_ < 4; jt_++) { \
        acc[mt_][jt_] = MFMA(AH[mt_], BH[jt_], acc[mt_][jt_]); \
        acc[mt_][jt_] = MFMA(AH[mt_], BL[jt_], acc[mt_][jt_]); \
        acc[mt_][jt_] = MFMA(AL[mt_], BH[jt_], acc[mt_][jt_]); \
    } \
} while (0)

    short8 A0h[4], A0l[4], B0h[4], B0l[4];
    short8 A1h[4], A1l[4], B1h[4], B1l[4];
    C3_LOAD(0, A0h, A0l, B0h, B0l);
#pragma unroll
    for (int it = 0; it < 9; it++) {
        C3_LOAD(it * 2 + 1, A1h, A1l, B1h, B1l);
        C3_MFMA(A0h, A0l, B0h, B0l);
        if (it < 8) C3_LOAD(it * 2 + 2, A0h, A0l, B0h, B0l);
        C3_MFMA(A1h, A1l, B1h, B1l);
    }
#undef C3_LOAD
#undef C3_MFMA

    float pa = prelu_a[0];
#pragma unroll
    for (int ph = 0; ph < 2; ph++) {
        __syncthreads();
#pragma unroll
        for (int mt = 0; mt < 4; mt++)
#pragma unroll
            for (int jt = 0; jt < 2; jt++)
#pragma unroll
                for (int r = 0; r < 4; r++)
                    Sp[w][(mt * 16 + q * 4 + r) * 32 + jt * 16 + lc] = acc[mt][ph * 2 + jt][r];
        __syncthreads();
#pragma unroll
        for (int gi = 0; gi < 2; gi++) {
            int g = tid + gi * 256;
            int j = g & 31, mg = g >> 5;
            int m = mg * 4;
            int jj = j0 + ph * 32 + j;
            if (jj >= 961) continue;
            float v[4];
#pragma unroll
            for (int i = 0; i < 4; i++) {
                int idx = (m + i) * 32 + j;
                v[i] = Sp[0][idx] + Sp[1][idx] + Sp[2][idx] + Sp[3][idx];
                v[i] = v[i] * sc[m + i] + sh[m + i];
                v[i] = v[i] >= 0.f ? v[i] : pa * v[i];
            }
            ushort_t a0, b0, a1, b1, a2, b2, a3, b3;
            split2(v[0], a0, b0); split2(v[1], a1, b1);
            split2(v[2], a2, b2); split2(v[3], a3, b3);
            *(ushort4*)(ebh + (size_t)jj * 64 + m) = make_ushort4(a0, a1, a2, a3);
            *(ushort4*)(ebl + (size_t)jj * 64 + m) = make_ushort4(b0, b1, b2, b3);
        }
    }
}

// ---------------------------------------------------------------------
// HSPA: S = e^T e -> sparsemax (Michelot) -> P^T bf16.
// Block owns 32 rows (2 groups of 16): GEMM keeps BOTH groups' accs in
// registers (acc[2][8], static idx) with 1-deep b-prefetch over the 61
// j-tiles; groups then dump->Michelot->PT-write sequentially through one
// 63 KB S buffer. grid (B, 31).
// ---------------------------------------------------------------------
__global__ __launch_bounds__(512) void hspa_mfma_kernel(
    const ushort_t* __restrict__ eh, const ushort_t* __restrict__ el,
    ushort_t* __restrict__ PT)
{
    const int PITCH = 978;
    __shared__ float S[16 * 978];
    int b = blockIdx.x, nb = blockIdx.y;
    const ushort_t* ebh = eh + (size_t)b * 1024 * 64;
    const ushort_t* ebl = el + (size_t)b * 1024 * 64;
    ushort_t* Pb = PT + (size_t)b * 1024 * 992;
    int tid = threadIdx.x, w = tid >> 6, l = tid & 63, lc = l & 15, q = l >> 4;
    int n0 = nb * 32;

    // A fragments: 2 row-groups x 2 k-halves
    short8 Ah[2][2], Al[2][2];
#pragma unroll
    for (int g = 0; g < 2; g++)
#pragma unroll
        for (int kh = 0; kh < 2; kh++) {
            size_t off = (size_t)(n0 + g * 16 + lc) * 64 + kh * 32 + q * 8;
            Ah[g][kh] = *(const short8*)(ebh + off);
            Al[g][kh] = *(const short8*)(ebl + off);
        }

    floatx4 acc[2][8];
#pragma unroll
    for (int g = 0; g < 2; g++)
#pragma unroll
        for (int s = 0; s < 8; s++) acc[g][s] = (floatx4){0.f, 0.f, 0.f, 0.f};

#define HS_LOADB(SLOT, BH0, BL0, BH1, BL1) do { \
    int jt_ = w + (SLOT) * 8; if (jt_ > 60) jt_ = 60; \
    size_t o_ = (size_t)(jt_ * 16 + lc) * 64 + q * 8; \
    BH0 = *(const short8*)(ebh + o_); \
    BL0 = *(const short8*)(ebl + o_); \
    BH1 = *(const short8*)(ebh + o_ + 32); \
    BL1 = *(const short8*)(ebl + o_ + 32); \
} while (0)

    {
        short8 b0h[2], b0l[2], b1h[2], b1l[2];
        HS_LOADB(0, b0h[0], b0l[0], b1h[0], b1l[0]);
#pragma unroll
        for (int s = 0; s < 8; s++) {
            const int cur = s & 1, nxt = cur ^ 1;
            if (s < 7) HS_LOADB(s + 1, b0h[nxt], b0l[nxt], b1h[nxt], b1l[nxt]);
#pragma unroll
            for (int g = 0; g < 2; g++) {
                floatx4 a = acc[g][s];
                a = MFMA(Ah[g][0], b0h[cur], a);
                a = MFMA(Ah[g][0], b0l[cur], a);
                a = MFMA(Al[g][0], b0h[cur], a);
                a = MFMA(Ah[g][1], b1h[cur], a);
                a = MFMA(Ah[g][1], b1l[cur], a);
                a = MFMA(Al[g][1], b1h[cur], a);
                acc[g][s] = a;
            }
        }
    }
#undef HS_LOADB

#pragma unroll
    for (int g = 0; g < 2; g++) {
        if (g) __syncthreads();           // prior group's PT-write done reading S
#pragma unroll
        for (int s = 0; s < 8; s++) {
            int jt = w + s * 8;
            if (jt < 61) {
                int j = jt * 16 + lc;
#pragma unroll
                for (int r = 0; r < 4; r++)
                    S[(q * 4 + r) * PITCH + j] = acc[g][s][r];
            }
        }
        __syncthreads();

        int r0 = w * 2, r1 = w * 2 + 1;
        float sv0[16], sv1[16];
        float mx0 = -INFINITY, mx1 = -INFINITY;
#pragma unroll
        for (int t = 0; t < 16; t++) {
            int j = l + t * 64;
            float s0 = (j < 961) ? S[r0 * PITCH + j] : -INFINITY;
            float s1 = (j < 961) ? S[r1 * PITCH + j] : -INFINITY;
            sv0[t] = s0; sv1[t] = s1;
            mx0 = fmaxf(mx0, s0); mx1 = fmaxf(mx1, s1);
        }
        for (int off = 32; off; off >>= 1) {
            mx0 = fmaxf(mx0, __shfl_xor(mx0, off));
            mx1 = fmaxf(mx1, __shfl_xor(mx1, off));
        }
#pragma unroll
        for (int t = 0; t < 16; t++) { sv0[t] -= mx0; sv1[t] -= mx1; }

        float tau0 = -1.f, tau1 = -1.f;
        for (int it = 0; it < 16; it++) {
            float s0 = 0.f, c0 = 0.f, s1 = 0.f, c1 = 0.f;
#pragma unroll
            for (int t = 0; t < 16; t++) {
                if (sv0[t] > tau0) { s0 += sv0[t]; c0 += 1.f; }
                if (sv1[t] > tau1) { s1 += sv1[t]; c1 += 1.f; }
            }
            for (int off = 32; off; off >>= 1) {
                s0 += __shfl_xor(s0, off); c0 += __shfl_xor(c0, off);
                s1 += __shfl_xor(s1, off); c1 += __shfl_xor(c1, off);
            }
            float nt0 = (s0 - 1.f) / c0;
            float nt1 = (s1 - 1.f) / c1;
            bool conv = (nt0 == tau0) && (nt1 == tau1);
            tau0 = nt0; tau1 = nt1;
            if (conv) break;
        }
#pragma unroll
        for (int t = 0; t < 16; t++) {
            int j = l + t * 64;
            if (j < 976) {
                S[r0 * PITCH + j] = (j < 961) ? fmaxf(sv0[t] - tau0, 0.f) : 0.f;
                S[r1 * PITCH + j] = (j < 961) ? fmaxf(sv1[t] - tau1, 0.f) : 0.f;
            }
        }
        __syncthreads();

        int nbase = n0 + g * 16;
        if (nbase < 976) {
            for (int j = tid; j < 976; j += 512) {
                union { ushort_t u[8]; uint4 v; } p0, p1;
#pragma unroll
                for (int r = 0; r < 8; r++)  p0.u[r] = f2bf(S[r * PITCH + j]);
#pragma unroll
                for (int r = 0; r < 8; r++)  p1.u[r] = f2bf(S[(8 + r) * PITCH + j]);
                ushort_t* dst = Pb + (size_t)j * 992 + nbase;
                *(uint4*)(dst) = p0.v;
                *(uint4*)(dst + 8) = p1.v;
            }
        }
    }
}

// ---------------------------------------------------------------------
// out = gat @ P + gat. grid (B, 16) batch-major.
// ---------------------------------------------------------------------
__global__ __launch_bounds__(256, 2) void out_mfma_kernel(
    const ushort_t* __restrict__ gat_nf, const ushort_t* __restrict__ PT,
    float* __restrict__ out)
{
    int b = blockIdx.x, jb = blockIdx.y;
    const ushort_t* gb = gat_nf + (size_t)b * 256 * 992;
    const ushort_t* Pb = PT + (size_t)b * 1024 * 992;
    float* ob = out + (size_t)b * 256 * 961;
    int tid = threadIdx.x, w = tid >> 6, l = tid & 63, lc = l & 15, q = l >> 4;
    int m0 = w * 64, j0 = jb * 64;

    floatx4 acc[4][4];
#pragma unroll
    for (int i = 0; i < 4; i++)
#pragma unroll
        for (int j = 0; j < 4; j++) acc[i][j] = (floatx4){0.f, 0.f, 0.f, 0.f};

#define OUT_LOAD(K0, AA, BB) do { \
    _Pragma("unroll") \
    for (int mt_ = 0; mt_ < 4; mt_++) \
        AA[mt_] = *(const short8*)(gb + (size_t)(m0 + mt_ * 16 + lc) * 992 + (K0) + q * 8); \
    _Pragma("unroll") \
    for (int jt_ = 0; jt_ < 4; jt_++) \
        BB[jt_] = *(const short8*)(Pb + (size_t)(j0 + jt_ * 16 + lc) * 992 + (K0) + q * 8); \
} while (0)
#define OUT_MFMA(AA, BB) do { \
    _Pragma("unroll") \
    for (int mt_ = 0; mt_ < 4; mt_++) \
    _Pragma("unroll") \
    for (int jt_ = 0; jt_ < 4; jt_++) \
        acc[mt_][jt_] = MFMA(AA[mt_], BB[jt_], acc[mt_][jt_]); \
} while (0)

    short8 a0[4], b0[4], a1[4], b1[4];
    OUT_LOAD(0, a0, b0);
    for (int k0 = 0; k0 < 960; k0 += 64) {
        OUT_LOAD(k0 + 32, a1, b1);
        OUT_MFMA(a0, b0);
        OUT_LOAD(k0 + 64, a0, b0);
        OUT_MFMA(a1, b1);
    }
    OUT_MFMA(a0, b0);   // k0 = 960
#undef OUT_LOAD
#undef OUT_MFMA

#pragma unroll
    for (int mt = 0; mt < 4; mt++) {
        int mb = m0 + mt * 16 + q * 4;
#pragma unroll
        for (int jt = 0; jt < 4; jt++) {
            int j = j0 + jt * 16 + lc;
            if (j >= 961) continue;
#pragma unroll
            for (int r = 0; r < 4; r++) {
                float g = bf2f(gb[(size_t)(mb + r) * 992 + j]);
                ob[(size_t)(mb + r) * 961 + j] = acc[mt][jt][r] + g;
            }
        }
    }
}

// =====================================================================
extern "C" void kernel_launch(void* const* d_in, const int* in_sizes, int n_in,
                              void* d_out, int out_size, void* d_ws, size_t ws_size,
                              hipStream_t stream)
{
    const float* zf      = (const float*)d_in[0];
    const float* xf      = (const float*)d_in[1];
    const float* Wq      = (const float*)d_in[2];
    const float* bq      = (const float*)d_in[3];
    const float* Ws      = (const float*)d_in[4];
    const float* bs      = (const float*)d_in[5];
    const float* Wg      = (const float*)d_in[6];
    const float* bg      = (const float*)d_in[7];
    const float* g_gamma = (const float*)d_in[8];
    const float* g_beta  = (const float*)d_in[9];
    const float* g_mean  = (const float*)d_in[10];
    const float* g_var   = (const float*)d_in[11];
    const float* Wfi     = (const float*)d_in[12];
    const float* bfi     = (const float*)d_in[13];
    const float* fi_gamma= (const float*)d_in[14];
    const float* fi_beta = (const float*)d_in[15];
    const float* fi_mean = (const float*)d_in[16];
    const float* fi_var  = (const float*)d_in[17];
    const float* Wm      = (const float*)d_in[18];
    const float* bm      = (const float*)d_in[19];
    const float* m_gamma = (const float*)d_in[20];
    const float* m_beta  = (const float*)d_in[21];
    const float* m_mean  = (const float*)d_in[22];
    const float* m_var   = (const float*)d_in[23];
    const float* prelu_a = (const float*)d_in[24];
    float* out = (float*)d_out;

    ushort_t* ws = (ushort_t*)d_ws;
    ushort_t* Wq_h  = ws + 0;         ushort_t* Wq_l  = ws + 65536;
    ushort_t* Ws_h  = ws + 131072;    ushort_t* Ws_l  = ws + 196608;
    ushort_t* Wg_h  = ws + 262144;    ushort_t* Wg_l  = ws + 327680;
    ushort_t* Wfi_h = ws + 393216;    ushort_t* Wfi_l = ws + 524288;
    ushort_t* wm_h  = ws + 655360;    ushort_t* wm_l  = ws + 802816;
    ushort_t* XT_h    = ws + 950272;      // 8,126,464 each
    ushort_t* XT_l    = ws + 9076736;
    ushort_t* xf_tT_h = ws + 17203200;
    ushort_t* xf_tT_l = ws + 25329664;
    ushort_t* zf_tT_h = ws + 33456128;    // 524,288 each
    ushort_t* zf_tT_l = ws + 33980416;
    ushort_t* zf_gT_h = ws + 34504704;
    ushort_t* zf_gT_l = ws + 35028992;
    ushort_t* xf_gT_h = ws + 35553280;
    ushort_t* xf_gT_l = ws + 43679744;
    ushort_t* gat_nf  = ws + 51806208;    // 8,126,464
    ushort_t* eT_h    = ws + 59932672;    // 2,097,152 each
    ushort_t* eT_l    = ws + 62029824;
    ushort_t* PT      = ws + 64126976;    // 32,505,856
    // gx lives INSIDE the PT region: written by fi, consumed by conv3x3,
    // then hspa overwrites the region with PT (strictly later in the stream).
    ushort_t* gxT_h   = ws + 64126976;    // 8,921,088
    ushort_t* gxT_l   = ws + 73048064;    // 8,921,088
    // embT aliases the XT region (XT dead after dualconv big).
    ushort_t* embT_h  = XT_h;
    ushort_t* embT_l  = XT_l;
    ushort_t* zfT_h   = ws + 96632832;    // 524,288 each
    ushort_t* zfT_l   = ws + 97157120;
    float* scsh       = (float*)(ws + 97681408);   // 2176 floats
    ushort_t* zgC_h   = ws + 97685760;    // 524,288 each
    ushort_t* zgC_l   = ws + 98210048;

    const float* sc_q  = scsh + 0,    *sh_q  = scsh + 256;
    const float* sc_s  = scsh + 512,  *sh_s  = scsh + 768;
    const float* sc_g  = scsh + 1024, *sh_g  = scsh + 1280;
    const float* sc_fi = scsh + 1536, *sh_fi = scsh + 1792;
    const float* sc_m  = scsh + 2048, *sh_m  = scsh + 2112;

    prep_all_kernel<<<1857, 256, 0, stream>>>(
        Wq, Ws, Wg, Wfi, Wm,
        bq, bs, bg, g_gamma, g_beta, g_mean, g_var,
        bfi, fi_gamma, fi_beta, fi_mean, fi_var,
        bm, m_gamma, m_beta, m_mean, m_var,
        Wq_h, Wq_l, Ws_h, Ws_l, Wg_h, Wg_l, Wfi_h, Wfi_l, wm_h, wm_l, scsh);

    transpose_in_kernel<<<dim3(31, 8, 32), 256, 0, stream>>>(xf, XT_h, XT_l, 961, 992);
    transpose_in_kernel<<<dim3(2, 8, 32), 256, 0, stream>>>(zf, zfT_h, zfT_l, 49, 64);

    // fused-halves dualconv, 16-row tiles: blockIdx.y = n-tile of 16
    dualconv_mfma_kernel<<<dim3(32, 62), 256, 0, stream>>>(
        XT_h, XT_l, Wq_h, Wq_l, Wg_h, Wg_l,
        sc_q, sh_q, sc_g, sh_g, 0, 1,
        xf_tT_h, xf_tT_l, xf_gT_h, xf_gT_l,
        nullptr, nullptr, 0, 256, 961, 992, 992);
    dualconv_mfma_kernel<<<dim3(32, 4), 256, 0, stream>>>(
        zfT_h, zfT_l, Ws_h, Ws_l, Wg_h, Wg_l,
        sc_s, sh_s, sc_g, sh_g, 0, 1,
        zf_tT_h, zf_tT_l, zf_gT_h, zf_gT_l,
        zgC_h, zgC_l, 64, 256, 49, 64, 64);

    attn_mfma_kernel<<<dim3(32, 16), 256, 0, stream>>>(
        xf_tT_h, xf_tT_l, zf_tT_h, zf_tT_l, zgC_h, zgC_l, embT_h, embT_l);

    halo_zero_kernel<<<16, 256, 0, stream>>>(gxT_h, gxT_l);

    fi_mfma_kernel<<<dim3(32, 62), 256, 0, stream>>>(
        embT_h, embT_l, xf_gT_h, xf_gT_l, Wfi_h, Wfi_l, sc_fi, sh_fi,
        gxT_h, gxT_l, gat_nf);

    conv3x3_mfma_kernel<<<dim3(32, 16), 256, 0, stream>>>(
        gxT_h, gxT_l, wm_h, wm_l, sc_m, sh_m, prelu_a, eT_h, eT_l);

    hspa_mfma_kernel<<<dim3(32, 31), 512, 0, stream>>>(eT_h, eT_l, PT);

    out_mfma_kernel<<<dim3(32, 16), 256, 0, stream>>>(gat_nf, PT, out);
}

// Round 8
// 563.353 us; speedup vs baseline: 1.1835x; 1.1835x over previous
//
#include <hip/hip_runtime.h>
#include <cstdint>
#include <cstddef>
#include <math.h>

typedef __attribute__((ext_vector_type(8))) short short8;
typedef __attribute__((ext_vector_type(4))) float floatx4;
typedef unsigned short ushort_t;

__device__ __forceinline__ ushort_t f2bf(float x) {
    union { float f; unsigned u; } v; v.f = x;
    unsigned r = v.u + 0x7FFF + ((v.u >> 16) & 1);
    return (ushort_t)(r >> 16);
}
__device__ __forceinline__ float bf2f(ushort_t h) {
    union { unsigned u; float f; } v; v.u = ((unsigned)h) << 16; return v.f;
}
__device__ __forceinline__ void split2(float v, ushort_t& h, ushort_t& l) {
    h = f2bf(v);
    l = f2bf(v - bf2f(h));
}

#define MFMA(a, b, c) __builtin_amdgcn_mfma_f32_16x16x32_bf16((a), (b), (c), 0, 0, 0)

__device__ __forceinline__ void gload_lds16(const void* g, void* l) {
    __builtin_amdgcn_global_load_lds(
        (const __attribute__((address_space(1))) unsigned*)g,
        (__attribute__((address_space(3))) unsigned*)l, 16, 0, 0);
}

// ---------------------------------------------------------------------
// prep_all: all weight hi/lo splits + Wm transpose + BN fold, one launch.
// ---------------------------------------------------------------------
__global__ void prep_all_kernel(
    const float* __restrict__ Wq, const float* __restrict__ Ws,
    const float* __restrict__ Wg, const float* __restrict__ Wfi,
    const float* __restrict__ Wm,
    const float* bq, const float* bs,
    const float* bg, const float* gg, const float* gb, const float* gm, const float* gv,
    const float* bfi, const float* fg, const float* fb, const float* fm, const float* fv,
    const float* bm, const float* mg, const float* mb, const float* mm, const float* mv,
    ushort_t* Wq_h, ushort_t* Wq_l, ushort_t* Ws_h, ushort_t* Ws_l,
    ushort_t* Wg_h, ushort_t* Wg_l, ushort_t* Wfi_h, ushort_t* Wfi_l,
    ushort_t* wm_h, ushort_t* wm_l, float* scsh)
{
    int bid = blockIdx.x, t = threadIdx.x;
    if (bid < 256) {
        int i = bid * 256 + t; ushort_t h, l; split2(Wq[i], h, l); Wq_h[i] = h; Wq_l[i] = l;
    } else if (bid < 512) {
        int i = (bid - 256) * 256 + t; ushort_t h, l; split2(Ws[i], h, l); Ws_h[i] = h; Ws_l[i] = l;
    } else if (bid < 768) {
        int i = (bid - 512) * 256 + t; ushort_t h, l; split2(Wg[i], h, l); Wg_h[i] = h; Wg_l[i] = l;
    } else if (bid < 1280) {
        int i = (bid - 768) * 256 + t; ushort_t h, l; split2(Wfi[i], h, l); Wfi_h[i] = h; Wfi_l[i] = l;
    } else if (bid < 1856) {
        int i = (bid - 1280) * 256 + t;  // [tap][m][c] flattened
        int c = i & 255, m = (i >> 8) & 63, tap = i >> 14;
        ushort_t h, l; split2(Wm[((size_t)m * 256 + c) * 9 + tap], h, l);
        wm_h[i] = h; wm_l[i] = l;
    } else {
        if (t < 256) {
            scsh[t] = 1.f;        scsh[256 + t] = bq[t];
            scsh[512 + t] = 1.f;  scsh[768 + t] = bs[t];
            float s = gg[t] * rsqrtf(gv[t] + 1e-5f);
            scsh[1024 + t] = s;   scsh[1280 + t] = gb[t] + s * (bg[t] - gm[t]);
            float s2 = fg[t] * rsqrtf(fv[t] + 1e-5f);
            scsh[1536 + t] = s2;  scsh[1792 + t] = fb[t] + s2 * (bfi[t] - fm[t]);
            if (t < 64) {
                float s3 = mg[t] * rsqrtf(mv[t] + 1e-5f);
                scsh[2048 + t] = s3; scsh[2112 + t] = mb[t] + s3 * (bm[t] - mm[t]);
            }
        }
    }
}

// halo-only zero of gxT (128 halo rows per batch, hi+lo)
__global__ void halo_zero_kernel(ushort_t* __restrict__ gxh, ushort_t* __restrict__ gxl) {
    int i = blockIdx.x * 256 + threadIdx.x;   // 0..4095
    int b = i >> 7, k = i & 127;
    int r;
    if (k < 33) r = k;
    else if (k < 66) r = 32 * 33 + (k - 33);
    else { int k2 = k - 66; r = ((k2 >> 1) + 1) * 33 + ((k2 & 1) ? 32 : 0); }
    uint4* ph = (uint4*)(gxh + ((size_t)b * 1089 + r) * 256);
    uint4* pl = (uint4*)(gxl + ((size_t)b * 1089 + r) * 256);
    uint4 z = make_uint4(0, 0, 0, 0);
#pragma unroll
    for (int s = 0; s < 32; s++) { ph[s] = z; pl[s] = z; }
}

// fp32 [B][256][Nsrc] -> bf16 hi/lo [B][Npad][256]
__global__ __launch_bounds__(256) void transpose_in_kernel(
    const float* __restrict__ in, ushort_t* __restrict__ oh, ushort_t* __restrict__ ol,
    int Nsrc, int Npad)
{
    int b = blockIdx.z;
    const float* ib = in + (size_t)b * 256 * Nsrc;
    ushort_t* obh = oh + (size_t)b * Npad * 256;
    ushort_t* obl = ol + (size_t)b * Npad * 256;
    __shared__ float tile[32][33];
    int n0 = blockIdx.x * 32, c0 = blockIdx.y * 32;
    int tx = threadIdx.x & 31, ty = threadIdx.x >> 5;
#pragma unroll
    for (int r = 0; r < 4; r++) {
        int c = c0 + ty + r * 8, n = n0 + tx;
        tile[ty + r * 8][tx] = (n < Nsrc) ? ib[(size_t)c * Nsrc + n] : 0.f;
    }
    __syncthreads();
#pragma unroll
    for (int r = 0; r < 4; r++) {
        int n = n0 + ty + r * 8, c = c0 + tx;
        if (n < Nsrc) {
            ushort_t h, l; split2(tile[tx][ty + r * 8], h, l);
            obh[(size_t)n * 256 + c] = h;
            obl[(size_t)n * 256 + c] = l;
        }
    }
}

// ---------------------------------------------------------------------
// dual conv1x1, FUSED halves + 32-row LDS-staged B (measured-best: 82 µs,
// 100 MB traffic — fused-16row and split-32row both worse). grid (B, 31).
// ---------------------------------------------------------------------
__global__ __launch_bounds__(256, 2) void dualconv_mfma_kernel(
    const ushort_t* __restrict__ Xh, const ushort_t* __restrict__ Xl,
    const ushort_t* __restrict__ W1h, const ushort_t* __restrict__ W1l,
    const ushort_t* __restrict__ W2h, const ushort_t* __restrict__ W2l,
    const float* __restrict__ sc1, const float* __restrict__ sh1,
    const float* __restrict__ sc2, const float* __restrict__ sh2,
    int relu1, int relu2,
    ushort_t* __restrict__ O1h, ushort_t* __restrict__ O1l,
    ushort_t* __restrict__ O2h, ushort_t* __restrict__ O2l,
    ushort_t* __restrict__ O2ch, ushort_t* __restrict__ O2cl, int cpitch,
    int K, int Nvalid, int NpadIn, int NpadOut)
{
    __shared__ ushort_t Bs[16384];   // 32 KB: hi rows @byte 0, lo rows @byte 16384
    int b = blockIdx.x;
    int n0 = blockIdx.y * 32;
    const ushort_t* Xbh = Xh + (size_t)b * NpadIn * K;
    const ushort_t* Xbl = Xl + (size_t)b * NpadIn * K;
    int tid = threadIdx.x, w = tid >> 6, l = tid & 63, lc = l & 15, q = l >> 4;
    int m0 = w * 64;

    // ---- stage B tile (swizzle: in-row byte ^= (row&7)<<4, folded into src) ----
#pragma unroll
    for (int r = 0; r < 8; r++) {
        int d = r * 4096 + w * 1024 + l * 16;      // linear byte in 32KB region
        int seg = d >> 14;                          // 0 = hi, 1 = lo
        int dr = d & 16383;
        int row = dr >> 9;
        int inrow = (dr & 511) ^ ((row & 7) << 4);
        int srow = n0 + row; if (srow > NpadIn - 1) srow = NpadIn - 1;
        const ushort_t* src = (seg ? Xbl : Xbh) + (size_t)srow * K + (inrow >> 1);
        char* dst = (char*)Bs + (r * 4096 + w * 1024);
        gload_lds16(src, dst);
    }
    __syncthreads();

#define DC_LOADA(K0, AH, AL) do { \
    _Pragma("unroll") \
    for (int mt_ = 0; mt_ < 4; mt_++) { \
        size_t off_ = (size_t)(m0 + mt_ * 16 + lc) * K + (K0) + q * 8; \
        AH[mt_] = *(const short8*)(Wh + off_); \
        AL[mt_] = *(const short8*)(Wl + off_); \
    } \
} while (0)
#define DC_LDSB(K0, BH, BL) do { \
    _Pragma("unroll") \
    for (int jt_ = 0; jt_ < 2; jt_++) { \
        int row_ = jt_ * 16 + lc; \
        int koff_ = (((K0) + q * 8) * 2) ^ ((row_ & 7) << 4); \
        BH[jt_] = *(const short8*)((const char*)Bs + row_ * 512 + koff_); \
        BL[jt_] = *(const short8*)((const char*)Bs + 16384 + row_ * 512 + koff_); \
    } \
} while (0)
#define DC_MFMA(AH, AL, BH, BL) do { \
    _Pragma("unroll") \
    for (int mt_ = 0; mt_ < 4; mt_++) \
    _Pragma("unroll") \
    for (int jt_ = 0; jt_ < 2; jt_++) { \
        acc[mt_][jt_] = MFMA(AH[mt_], BH[jt_], acc[mt_][jt_]); \
        acc[mt_][jt_] = MFMA(AH[mt_], BL[jt_], acc[mt_][jt_]); \
        acc[mt_][jt_] = MFMA(AL[mt_], BH[jt_], acc[mt_][jt_]); \
    } \
} while (0)

    for (int half = 0; half < 2; half++) {
        const ushort_t* Wh = half ? W2h : W1h;
        const ushort_t* Wl = half ? W2l : W1l;
        const float* sc = half ? sc2 : sc1;
        const float* sh = half ? sh2 : sh1;
        int relu = half ? relu2 : relu1;
        ushort_t* Obh = (half ? O2h : O1h) + (size_t)b * NpadOut * 256;
        ushort_t* Obl = (half ? O2l : O1l) + (size_t)b * NpadOut * 256;

        floatx4 acc[4][2];
#pragma unroll
        for (int i = 0; i < 4; i++)
#pragma unroll
            for (int j = 0; j < 2; j++) acc[i][j] = (floatx4){0.f, 0.f, 0.f, 0.f};

        short8 ah0[4], al0[4], ah1[4], al1[4], bh[2], bl[2];
        DC_LOADA(0, ah0, al0);
        for (int k0 = 0; k0 < K; k0 += 64) {
            DC_LOADA(k0 + 32, ah1, al1);
            DC_LDSB(k0, bh, bl);
            DC_MFMA(ah0, al0, bh, bl);
            if (k0 + 64 < K) DC_LOADA(k0 + 64, ah0, al0);
            DC_LDSB(k0 + 32, bh, bl);
            DC_MFMA(ah1, al1, bh, bl);
        }

#pragma unroll
        for (int mt = 0; mt < 4; mt++) {
            int mb = m0 + mt * 16 + q * 4;
            float s0 = sc[mb], s1 = sc[mb + 1], s2 = sc[mb + 2], s3 = sc[mb + 3];
            float h0 = sh[mb], h1 = sh[mb + 1], h2 = sh[mb + 2], h3 = sh[mb + 3];
#pragma unroll
            for (int jt = 0; jt < 2; jt++) {
                int n = n0 + jt * 16 + lc;
                if (n >= Nvalid) continue;
                float v0 = acc[mt][jt][0] * s0 + h0;
                float v1 = acc[mt][jt][1] * s1 + h1;
                float v2 = acc[mt][jt][2] * s2 + h2;
                float v3 = acc[mt][jt][3] * s3 + h3;
                if (relu) { v0 = fmaxf(v0, 0.f); v1 = fmaxf(v1, 0.f); v2 = fmaxf(v2, 0.f); v3 = fmaxf(v3, 0.f); }
                ushort_t e0, f0, e1, f1, e2, f2, e3, f3;
                split2(v0, e0, f0); split2(v1, e1, f1); split2(v2, e2, f2); split2(v3, e3, f3);
                *(ushort4*)(Obh + (size_t)n * 256 + mb) = make_ushort4(e0, e1, e2, e3);
                *(ushort4*)(Obl + (size_t)n * 256 + mb) = make_ushort4(f0, f1, f2, f3);
                if (half && O2ch) {
                    O2ch[((size_t)b * 256 + mb + 0) * cpitch + n] = e0;
                    O2ch[((size_t)b * 256 + mb + 1) * cpitch + n] = e1;
                    O2ch[((size_t)b * 256 + mb + 2) * cpitch + n] = e2;
                    O2ch[((size_t)b * 256 + mb + 3) * cpitch + n] = e3;
                    O2cl[((size_t)b * 256 + mb + 0) * cpitch + n] = f0;
                    O2cl[((size_t)b * 256 + mb + 1) * cpitch + n] = f1;
                    O2cl[((size_t)b * 256 + mb + 2) * cpitch + n] = f2;
                    O2cl[((size_t)b * 256 + mb + 3) * cpitch + n] = f3;
                }
            }
        }
    }
#undef DC_LOADA
#undef DC_LDSB
#undef DC_MFMA
}

// ---------------------------------------------------------------------
// FUSED attention + fi conv. grid (B, 31), 32 n-rows per block, 4 waves.
// sim(32x49) -> softmax -> emb(32x256, kept in LDS) -> fi conv k<256 on
// emb, re-stage LDS with xf_g, fi conv k>=256. Eliminates the embT
// global round-trip (66 MB). LDS = 8.7K sim + 18K attn + 32K staged-B.
// ---------------------------------------------------------------------
__global__ __launch_bounds__(256, 2) void attnfi_mfma_kernel(
    const ushort_t* __restrict__ xth, const ushort_t* __restrict__ xtl,
    const ushort_t* __restrict__ zth, const ushort_t* __restrict__ ztl,
    const ushort_t* __restrict__ zgh, const ushort_t* __restrict__ zgl,
    const ushort_t* __restrict__ Gh, const ushort_t* __restrict__ Gl,
    const ushort_t* __restrict__ Wh, const ushort_t* __restrict__ Wl,
    const float* __restrict__ sc, const float* __restrict__ sh,
    ushort_t* __restrict__ gxh, ushort_t* __restrict__ gxl,
    ushort_t* __restrict__ gat_nf)
{
    __shared__ float SM[32][68];                    // 8704 B
    __shared__ ushort_t AWh[32][72], AWl[32][72];   // 9216 B
    __shared__ ushort_t EM[16384];                  // 32 KB staged B (emb, then xf_g)

    int b = blockIdx.x, nb0 = blockIdx.y * 32;
    int tid = threadIdx.x, w = tid >> 6, l = tid & 63, lc = l & 15, q = l >> 4;
    const ushort_t* xhb = xth + (size_t)b * 992 * 256;
    const ushort_t* xlb = xtl + (size_t)b * 992 * 256;
    const ushort_t* zhb = zth + (size_t)b * 64 * 256;
    const ushort_t* zlb = ztl + (size_t)b * 64 * 256;
    const ushort_t* ghb = zgh + (size_t)b * 256 * 64;
    const ushort_t* glb = zgl + (size_t)b * 256 * 64;
    const ushort_t* Gbh = Gh + (size_t)b * 992 * 256;
    const ushort_t* Gbl = Gl + (size_t)b * 992 * 256;
    ushort_t* gxhb = gxh + (size_t)b * 1089 * 256;
    ushort_t* gxlb = gxl + (size_t)b * 1089 * 256;
    ushort_t* gn = gat_nf + (size_t)b * 256 * 992;
    int m0 = w * 64;

    // ---- P1: sim = xf_t . zf_t^T  (wave: row-group w>>1, ct pair (w&1)*2) ----
    {
        int rg = w >> 1, c2 = (w & 1) * 2;
        size_t arow = (size_t)(nb0 + rg * 16 + lc) * 256;
        size_t brow0 = (size_t)(c2 * 16 + lc) * 256;
        size_t brow1 = (size_t)((c2 + 1) * 16 + lc) * 256;
        floatx4 s0 = (floatx4){0.f, 0.f, 0.f, 0.f};
        floatx4 s1 = (floatx4){0.f, 0.f, 0.f, 0.f};
        for (int k0 = 0; k0 < 256; k0 += 32) {
            short8 ah = *(const short8*)(xhb + arow + k0 + q * 8);
            short8 al = *(const short8*)(xlb + arow + k0 + q * 8);
            short8 b0h = *(const short8*)(zhb + brow0 + k0 + q * 8);
            short8 b0l = *(const short8*)(zlb + brow0 + k0 + q * 8);
            short8 b1h = *(const short8*)(zhb + brow1 + k0 + q * 8);
            short8 b1l = *(const short8*)(zlb + brow1 + k0 + q * 8);
            s0 = MFMA(ah, b0h, s0); s0 = MFMA(ah, b0l, s0); s0 = MFMA(al, b0h, s0);
            s1 = MFMA(ah, b1h, s1); s1 = MFMA(ah, b1l, s1); s1 = MFMA(al, b1h, s1);
        }
#pragma unroll
        for (int r = 0; r < 4; r++) {
            SM[rg * 16 + q * 4 + r][c2 * 16 + lc] = s0[r];
            SM[rg * 16 + q * 4 + r][(c2 + 1) * 16 + lc] = s1[r];
        }
    }
    __syncthreads();

    // ---- softmax over m (49 valid) per row ----
    if (tid < 32) {
        float mx = -INFINITY;
        for (int m = 0; m < 49; m++) mx = fmaxf(mx, SM[tid][m]);
        float sum = 0.f;
        for (int m = 0; m < 49; m++) { float e = __expf(SM[tid][m] - mx); SM[tid][m] = e; sum += e; }
        float inv = 1.f / sum;
        for (int m = 0; m < 64; m++) {
            float vv = (m < 49) ? SM[tid][m] * inv : 0.f;
            ushort_t hh, ll; split2(vv, hh, ll);
            AWh[tid][m] = hh; AWl[tid][m] = ll;
        }
    }
    __syncthreads();

    // ---- P2: emb = zg . attn -> EM (swizzled bf16 hi/lo, rows n) ----
#pragma unroll
    for (int rg = 0; rg < 2; rg++) {
        short8 pah0 = *(const short8*)(&AWh[rg * 16 + lc][q * 8]);
        short8 pal0 = *(const short8*)(&AWl[rg * 16 + lc][q * 8]);
        short8 pah1 = *(const short8*)(&AWh[rg * 16 + lc][32 + q * 8]);
        short8 pal1 = *(const short8*)(&AWl[rg * 16 + lc][32 + q * 8]);
#pragma unroll
        for (int t = 0; t < 4; t++) {
            int ct = w * 4 + t;
            size_t brow = (size_t)(ct * 16 + lc) * 64;
            short8 bh0 = *(const short8*)(ghb + brow + q * 8);
            short8 bl0 = *(const short8*)(glb + brow + q * 8);
            short8 bh1 = *(const short8*)(ghb + brow + 32 + q * 8);
            short8 bl1 = *(const short8*)(glb + brow + 32 + q * 8);
            floatx4 a = (floatx4){0.f, 0.f, 0.f, 0.f};
            a = MFMA(pah0, bh0, a); a = MFMA(pah0, bl0, a); a = MFMA(pal0, bh0, a);
            a = MFMA(pah1, bh1, a); a = MFMA(pah1, bl1, a); a = MFMA(pal1, bh1, a);
            int cc = ct * 16 + lc;
#pragma unroll
            for (int r = 0; r < 4; r++) {
                int n = rg * 16 + q * 4 + r;
                int off = n * 512 + ((cc * 2) ^ ((n & 7) << 4));
                ushort_t hh, ll; split2(a[r], hh, ll);
                *(ushort_t*)((char*)EM + off) = hh;
                *(ushort_t*)((char*)EM + 16384 + off) = ll;
            }
        }
    }
    __syncthreads();

    // ---- P3: fi conv, phase A (k=0..255, B=emb) then B (k>=256, B=xf_g) ----
#define AF_LOADA(K0, AH, AL) do { \
    _Pragma("unroll") \
    for (int mt_ = 0; mt_ < 4; mt_++) { \
        size_t off_ = (size_t)(m0 + mt_ * 16 + lc) * 512 + (K0) + q * 8; \
        AH[mt_] = *(const short8*)(Wh + off_); \
        AL[mt_] = *(const short8*)(Wl + off_); \
    } \
} while (0)
#define AF_LDSB(K0, BH, BL) do { \
    _Pragma("unroll") \
    for (int jt_ = 0; jt_ < 2; jt_++) { \
        int row_ = jt_ * 16 + lc; \
        int koff_ = (((K0) + q * 8) * 2) ^ ((row_ & 7) << 4); \
        BH[jt_] = *(const short8*)((const char*)EM + row_ * 512 + koff_); \
        BL[jt_] = *(const short8*)((const char*)EM + 16384 + row_ * 512 + koff_); \
    } \
} while (0)
#define AF_MFMA(AH, AL, BH, BL) do { \
    _Pragma("unroll") \
    for (int mt_ = 0; mt_ < 4; mt_++) \
    _Pragma("unroll") \
    for (int jt_ = 0; jt_ < 2; jt_++) { \
        acc[mt_][jt_] = MFMA(AH[mt_], BH[jt_], acc[mt_][jt_]); \
        acc[mt_][jt_] = MFMA(AH[mt_], BL[jt_], acc[mt_][jt_]); \
        acc[mt_][jt_] = MFMA(AL[mt_], BH[jt_], acc[mt_][jt_]); \
    } \
} while (0)

    floatx4 acc[4][2];
#pragma unroll
    for (int i = 0; i < 4; i++)
#pragma unroll
        for (int j = 0; j < 2; j++) acc[i][j] = (floatx4){0.f, 0.f, 0.f, 0.f};

    {
        short8 ah0[4], al0[4], ah1[4], al1[4], bh[2], bl[2];
        AF_LOADA(0, ah0, al0);
        for (int kk = 0; kk < 256; kk += 64) {
            AF_LOADA(kk + 32, ah1, al1);
            AF_LDSB(kk, bh, bl);
            AF_MFMA(ah0, al0, bh, bl);
            if (kk + 64 < 256) AF_LOADA(kk + 64, ah0, al0);
            AF_LDSB(kk + 32, bh, bl);
            AF_MFMA(ah1, al1, bh, bl);
        }
    }
    __syncthreads();            // all waves done reading emb from EM

    // stage xf_g (32 rows, swizzled via pre-swizzled global src) into EM
#pragma unroll
    for (int r = 0; r < 8; r++) {
        int d = r * 4096 + w * 1024 + l * 16;
        int seg = d >> 14;
        int dr = d & 16383;
        int row = dr >> 9;
        int inrow = (dr & 511) ^ ((row & 7) << 4);
        int srow = nb0 + row; if (srow > 991) srow = 991;
        const ushort_t* src = (seg ? Gbl : Gbh) + (size_t)srow * 256 + (inrow >> 1);
        gload_lds16(src, (char*)EM + d);
    }
    __syncthreads();            // staging drained

    {
        short8 ah0[4], al0[4], ah1[4], al1[4], bh[2], bl[2];
        AF_LOADA(256, ah0, al0);
        for (int kk = 0; kk < 256; kk += 64) {
            AF_LOADA(256 + kk + 32, ah1, al1);
            AF_LDSB(kk, bh, bl);
            AF_MFMA(ah0, al0, bh, bl);
            if (kk + 64 < 256) AF_LOADA(256 + kk + 64, ah0, al0);
            AF_LDSB(kk + 32, bh, bl);
            AF_MFMA(ah1, al1, bh, bl);
        }
    }
#undef AF_LOADA
#undef AF_LDSB
#undef AF_MFMA

    // ---- epilogue: BN+relu, write gx (halo layout) + gat_nf ----
#pragma unroll
    for (int mt = 0; mt < 4; mt++) {
        int mb = m0 + mt * 16 + q * 4;
        float s0 = sc[mb], s1 = sc[mb + 1], s2 = sc[mb + 2], s3 = sc[mb + 3];
        float h0 = sh[mb], h1 = sh[mb + 1], h2 = sh[mb + 2], h3 = sh[mb + 3];
#pragma unroll
        for (int jt = 0; jt < 2; jt++) {
            int n = nb0 + jt * 16 + lc;
            if (n >= 961) continue;
            float v0 = fmaxf(acc[mt][jt][0] * s0 + h0, 0.f);
            float v1 = fmaxf(acc[mt][jt][1] * s1 + h1, 0.f);
            float v2 = fmaxf(acc[mt][jt][2] * s2 + h2, 0.f);
            float v3 = fmaxf(acc[mt][jt][3] * s3 + h3, 0.f);
            ushort_t a0, b0, a1, b1, a2, b2, a3, b3;
            split2(v0, a0, b0); split2(v1, a1, b1); split2(v2, a2, b2); split2(v3, a3, b3);
            int hh = n / 31, ww2 = n - hh * 31;
            int row = (hh + 1) * 33 + (ww2 + 1);
            *(ushort4*)(gxhb + (size_t)row * 256 + mb) = make_ushort4(a0, a1, a2, a3);
            *(ushort4*)(gxlb + (size_t)row * 256 + mb) = make_ushort4(b0, b1, b2, b3);
            gn[(size_t)(mb + 0) * 992 + n] = a0;
            gn[(size_t)(mb + 1) * 992 + n] = a1;
            gn[(size_t)(mb + 2) * 992 + n] = a2;
            gn[(size_t)(mb + 3) * 992 + n] = a3;
        }
    }
}

// ---------------------------------------------------------------------
// conv3x3 split-K: block = 4 waves over ONE 64m x 64j tile, 72 (tap,k0)
// steps split 18/wave (k0-major, tap-fast), 1-deep register double-buffer,
// partials reduced in LDS in two 32j phases. grid (B, 16) batch-major.
// ---------------------------------------------------------------------
__global__ __launch_bounds__(256, 2) void conv3x3_mfma_kernel(
    const ushort_t* __restrict__ gxh, const ushort_t* __restrict__ gxl,
    const ushort_t* __restrict__ wmh, const ushort_t* __restrict__ wml,
    const float* __restrict__ sc, const float* __restrict__ sh,
    const float* __restrict__ prelu_a,
    ushort_t* __restrict__ eh, ushort_t* __restrict__ el)
{
    __shared__ float Sp[4][2048];   // 4 waves x (64m x 32j) partials, 32 KB
    int b = blockIdx.x;
    const ushort_t* gxhb = gxh + (size_t)b * 1089 * 256;
    const ushort_t* gxlb = gxl + (size_t)b * 1089 * 256;
    ushort_t* ebh = eh + (size_t)b * 1024 * 64;
    ushort_t* ebl = el + (size_t)b * 1024 * 64;
    int tid = threadIdx.x, w = tid >> 6, l = tid & 63, lc = l & 15, q = l >> 4;
    int j0 = blockIdx.y * 64;

    int base[4];
#pragma unroll
    for (int jt = 0; jt < 4; jt++) {
        int j = j0 + jt * 16 + lc; if (j > 960) j = 960;
        int hh = j / 31, ww2 = j - hh * 31;
        base[jt] = (hh + 1) * 33 + (ww2 + 1);
    }

    floatx4 acc[4][4];
#pragma unroll
    for (int i = 0; i < 4; i++)
#pragma unroll
        for (int j = 0; j < 4; j++) acc[i][j] = (floatx4){0.f, 0.f, 0.f, 0.f};

#define C3_LOAD(SL, AH, AL, BH, BL) do { \
    int sl_ = (SL); \
    int tap_ = (sl_ >= 9) ? sl_ - 9 : sl_; \
    int k0_ = (w * 2 + ((sl_ >= 9) ? 1 : 0)) * 32; \
    int doff_ = (tap_ / 3 - 1) * 33 + (tap_ % 3 - 1); \
    const ushort_t* wth_ = wmh + tap_ * 16384; \
    const ushort_t* wtl_ = wml + tap_ * 16384; \
    _Pragma("unroll") \
    for (int mt_ = 0; mt_ < 4; mt_++) { \
        size_t off_ = (size_t)(mt_ * 16 + lc) * 256 + k0_ + q * 8; \
        AH[mt_] = *(const short8*)(wth_ + off_); \
        AL[mt_] = *(const short8*)(wtl_ + off_); \
    } \
    _Pragma("unroll") \
    for (int jt_ = 0; jt_ < 4; jt_++) { \
        size_t off_ = (size_t)(base[jt_] + doff_) * 256 + k0_ + q * 8; \
        BH[jt_] = *(const short8*)(gxhb + off_); \
        BL[jt_] = *(const short8*)(gxlb + off_); \
    } \
} while (0)
#define C3_MFMA(AH, AL, BH, BL) do { \
    _Pragma("unroll") \
    for (int mt_ = 0; mt_ < 4; mt_++) \
    _Pragma("unroll") \
    for (int jt_ = 0; jt_ < 4; jt_++) { \
        acc[mt_][jt_] = MFMA(AH[mt_], BH[jt_], acc[mt_][jt_]); \
        acc[mt_][jt_] = MFMA(AH[mt_], BL[jt_], acc[mt_][jt_]); \
        acc[mt_][jt_] = MFMA(AL[mt_], BH[jt_], acc[mt_][jt_]); \
    } \
} while (0)

    short8 A0h[4], A0l[4], B0h[4], B0l[4];
    short8 A1h[4], A1l[4], B1h[4], B1l[4];
    C3_LOAD(0, A0h, A0l, B0h, B0l);
#pragma unroll
    for (int it = 0; it < 9; it++) {
        C3_LOAD(it * 2 + 1, A1h, A1l, B1h, B1l);
        C3_MFMA(A0h, A0l, B0h, B0l);
        if (it < 8) C3_LOAD(it * 2 + 2, A0h, A0l, B0h, B0l);
        C3_MFMA(A1h, A1l, B1h, B1l);
    }
#undef C3_LOAD
#undef C3_MFMA

    float pa = prelu_a[0];
#pragma unroll
    for (int ph = 0; ph < 2; ph++) {
        __syncthreads();
#pragma unroll
        for (int mt = 0; mt < 4; mt++)
#pragma unroll
            for (int jt = 0; jt < 2; jt++)
#pragma unroll
                for (int r = 0; r < 4; r++)
                    Sp[w][(mt * 16 + q * 4 + r) * 32 + jt * 16 + lc] = acc[mt][ph * 2 + jt][r];
        __syncthreads();
#pragma unroll
        for (int gi = 0; gi < 2; gi++) {
            int g = tid + gi * 256;
            int j = g & 31, mg = g >> 5;
            int m = mg * 4;
            int jj = j0 + ph * 32 + j;
            if (jj >= 961) continue;
            float v[4];
#pragma unroll
            for (int i = 0; i < 4; i++) {
                int idx = (m + i) * 32 + j;
                v[i] = Sp[0][idx] + Sp[1][idx] + Sp[2][idx] + Sp[3][idx];
                v[i] = v[i] * sc[m + i] + sh[m + i];
                v[i] = v[i] >= 0.f ? v[i] : pa * v[i];
            }
            ushort_t a0, b0, a1, b1, a2, b2, a3, b3;
            split2(v[0], a0, b0); split2(v[1], a1, b1);
            split2(v[2], a2, b2); split2(v[3], a3, b3);
            *(ushort4*)(ebh + (size_t)jj * 64 + m) = make_ushort4(a0, a1, a2, a3);
            *(ushort4*)(ebl + (size_t)jj * 64 + m) = make_ushort4(b0, b1, b2, b3);
        }
    }
}

// ---------------------------------------------------------------------
// HSPA: S = e^T e -> sparsemax (Michelot) -> P^T bf16.
// Block owns 32 rows (2 groups of 16): GEMM keeps BOTH groups' accs in
// registers (acc[2][8], static idx) with 1-deep b-prefetch over the 61
// j-tiles; groups then dump->Michelot->PT-write sequentially through one
// 63 KB S buffer. grid (B, 31).
// ---------------------------------------------------------------------
__global__ __launch_bounds__(512) void hspa_mfma_kernel(
    const ushort_t* __restrict__ eh, const ushort_t* __restrict__ el,
    ushort_t* __restrict__ PT)
{
    const int PITCH = 978;
    __shared__ float S[16 * 978];
    int b = blockIdx.x, nb = blockIdx.y;
    const ushort_t* ebh = eh + (size_t)b * 1024 * 64;
    const ushort_t* ebl = el + (size_t)b * 1024 * 64;
    ushort_t* Pb = PT + (size_t)b * 1024 * 992;
    int tid = threadIdx.x, w = tid >> 6, l = tid & 63, lc = l & 15, q = l >> 4;
    int n0 = nb * 32;

    // A fragments: 2 row-groups x 2 k-halves
    short8 Ah[2][2], Al[2][2];
#pragma unroll
    for (int g = 0; g < 2; g++)
#pragma unroll
        for (int kh = 0; kh < 2; kh++) {
            size_t off = (size_t)(n0 + g * 16 + lc) * 64 + kh * 32 + q * 8;
            Ah[g][kh] = *(const short8*)(ebh + off);
            Al[g][kh] = *(const short8*)(ebl + off);
        }

    floatx4 acc[2][8];
#pragma unroll
    for (int g = 0; g < 2; g++)
#pragma unroll
        for (int s = 0; s < 8; s++) acc[g][s] = (floatx4){0.f, 0.f, 0.f, 0.f};

#define HS_LOADB(SLOT, BH0, BL0, BH1, BL1) do { \
    int jt_ = w + (SLOT) * 8; if (jt_ > 60) jt_ = 60; \
    size_t o_ = (size_t)(jt_ * 16 + lc) * 64 + q * 8; \
    BH0 = *(const short8*)(ebh + o_); \
    BL0 = *(const short8*)(ebl + o_); \
    BH1 = *(const short8*)(ebh + o_ + 32); \
    BL1 = *(const short8*)(ebl + o_ + 32); \
} while (0)

    {
        short8 b0h[2], b0l[2], b1h[2], b1l[2];
        HS_LOADB(0, b0h[0], b0l[0], b1h[0], b1l[0]);
#pragma unroll
        for (int s = 0; s < 8; s++) {
            const int cur = s & 1, nxt = cur ^ 1;
            if (s < 7) HS_LOADB(s + 1, b0h[nxt], b0l[nxt], b1h[nxt], b1l[nxt]);
#pragma unroll
            for (int g = 0; g < 2; g++) {
                floatx4 a = acc[g][s];
                a = MFMA(Ah[g][0], b0h[cur], a);
                a = MFMA(Ah[g][0], b0l[cur], a);
                a = MFMA(Al[g][0], b0h[cur], a);
                a = MFMA(Ah[g][1], b1h[cur], a);
                a = MFMA(Ah[g][1], b1l[cur], a);
                a = MFMA(Al[g][1], b1h[cur], a);
                acc[g][s] = a;
            }
        }
    }
#undef HS_LOADB

#pragma unroll
    for (int g = 0; g < 2; g++) {
        if (g) __syncthreads();           // prior group's PT-write done reading S
#pragma unroll
        for (int s = 0; s < 8; s++) {
            int jt = w + s * 8;
            if (jt < 61) {
                int j = jt * 16 + lc;
#pragma unroll
                for (int r = 0; r < 4; r++)
                    S[(q * 4 + r) * PITCH + j] = acc[g][s][r];
            }
        }
        __syncthreads();

        int r0 = w * 2, r1 = w * 2 + 1;
        float sv0[16], sv1[16];
        float mx0 = -INFINITY, mx1 = -INFINITY;
#pragma unroll
        for (int t = 0; t < 16; t++) {
            int j = l + t * 64;
            float s0 = (j < 961) ? S[r0 * PITCH + j] : -INFINITY;
            float s1 = (j < 961) ? S[r1 * PITCH + j] : -INFINITY;
            sv0[t] = s0; sv1[t] = s1;
            mx0 = fmaxf(mx0, s0); mx1 = fmaxf(mx1, s1);
        }
        for (int off = 32; off; off >>= 1) {
            mx0 = fmaxf(mx0, __shfl_xor(mx0, off));
            mx1 = fmaxf(mx1, __shfl_xor(mx1, off));
        }
#pragma unroll
        for (int t = 0; t < 16; t++) { sv0[t] -= mx0; sv1[t] -= mx1; }

        float tau0 = -1.f, tau1 = -1.f;
        for (int it = 0; it < 16; it++) {
            float s0 = 0.f, c0 = 0.f, s1 = 0.f, c1 = 0.f;
#pragma unroll
            for (int t = 0; t < 16; t++) {
                if (sv0[t] > tau0) { s0 += sv0[t]; c0 += 1.f; }
                if (sv1[t] > tau1) { s1 += sv1[t]; c1 += 1.f; }
            }
            for (int off = 32; off; off >>= 1) {
                s0 += __shfl_xor(s0, off); c0 += __shfl_xor(c0, off);
                s1 += __shfl_xor(s1, off); c1 += __shfl_xor(c1, off);
            }
            float nt0 = (s0 - 1.f) / c0;
            float nt1 = (s1 - 1.f) / c1;
            bool conv = (nt0 == tau0) && (nt1 == tau1);
            tau0 = nt0; tau1 = nt1;
            if (conv) break;
        }
#pragma unroll
        for (int t = 0; t < 16; t++) {
            int j = l + t * 64;
            if (j < 976) {
                S[r0 * PITCH + j] = (j < 961) ? fmaxf(sv0[t] - tau0, 0.f) : 0.f;
                S[r1 * PITCH + j] = (j < 961) ? fmaxf(sv1[t] - tau1, 0.f) : 0.f;
            }
        }
        __syncthreads();

        int nbase = n0 + g * 16;
        if (nbase < 976) {
            for (int j = tid; j < 976; j += 512) {
                union { ushort_t u[8]; uint4 v; } p0, p1;
#pragma unroll
                for (int r = 0; r < 8; r++)  p0.u[r] = f2bf(S[r * PITCH + j]);
#pragma unroll
                for (int r = 0; r < 8; r++)  p1.u[r] = f2bf(S[(8 + r) * PITCH + j]);
                ushort_t* dst = Pb + (size_t)j * 992 + nbase;
                *(uint4*)(dst) = p0.v;
                *(uint4*)(dst + 8) = p1.v;
            }
        }
    }
}

// ---------------------------------------------------------------------
// out = gat @ P + gat. grid (B, 16) batch-major.
// ---------------------------------------------------------------------
__global__ __launch_bounds__(256, 2) void out_mfma_kernel(
    const ushort_t* __restrict__ gat_nf, const ushort_t* __restrict__ PT,
    float* __restrict__ out)
{
    int b = blockIdx.x, jb = blockIdx.y;
    const ushort_t* gb = gat_nf + (size_t)b * 256 * 992;
    const ushort_t* Pb = PT + (size_t)b * 1024 * 992;
    float* ob = out + (size_t)b * 256 * 961;
    int tid = threadIdx.x, w = tid >> 6, l = tid & 63, lc = l & 15, q = l >> 4;
    int m0 = w * 64, j0 = jb * 64;

    floatx4 acc[4][4];
#pragma unroll
    for (int i = 0; i < 4; i++)
#pragma unroll
        for (int j = 0; j < 4; j++) acc[i][j] = (floatx4){0.f, 0.f, 0.f, 0.f};

#define OUT_LOAD(K0, AA, BB) do { \
    _Pragma("unroll") \
    for (int mt_ = 0; mt_ < 4; mt_++) \
        AA[mt_] = *(const short8*)(gb + (size_t)(m0 + mt_ * 16 + lc) * 992 + (K0) + q * 8); \
    _Pragma("unroll") \
    for (int jt_ = 0; jt_ < 4; jt_++) \
        BB[jt_] = *(const short8*)(Pb + (size_t)(j0 + jt_ * 16 + lc) * 992 + (K0) + q * 8); \
} while (0)
#define OUT_MFMA(AA, BB) do { \
    _Pragma("unroll") \
    for (int mt_ = 0; mt_ < 4; mt_++) \
    _Pragma("unroll") \
    for (int jt_ = 0; jt_ < 4; jt_++) \
        acc[mt_][jt_] = MFMA(AA[mt_], BB[jt_], acc[mt_][jt_]); \
} while (0)

    short8 a0[4], b0[4], a1[4], b1[4];
    OUT_LOAD(0, a0, b0);
    for (int k0 = 0; k0 < 960; k0 += 64) {
        OUT_LOAD(k0 + 32, a1, b1);
        OUT_MFMA(a0, b0);
        OUT_LOAD(k0 + 64, a0, b0);
        OUT_MFMA(a1, b1);
    }
    OUT_MFMA(a0, b0);   // k0 = 960
#undef OUT_LOAD
#undef OUT_MFMA

#pragma unroll
    for (int mt = 0; mt < 4; mt++) {
        int mb = m0 + mt * 16 + q * 4;
#pragma unroll
        for (int jt = 0; jt < 4; jt++) {
            int j = j0 + jt * 16 + lc;
            if (j >= 961) continue;
#pragma unroll
            for (int r = 0; r < 4; r++) {
                float g = bf2f(gb[(size_t)(mb + r) * 992 + j]);
                ob[(size_t)(mb + r) * 961 + j] = acc[mt][jt][r] + g;
            }
        }
    }
}

// =====================================================================
extern "C" void kernel_launch(void* const* d_in, const int* in_sizes, int n_in,
                              void* d_out, int out_size, void* d_ws, size_t ws_size,
                              hipStream_t stream)
{
    const float* zf      = (const float*)d_in[0];
    const float* xf      = (const float*)d_in[1];
    const float* Wq      = (const float*)d_in[2];
    const float* bq      = (const float*)d_in[3];
    const float* Ws      = (const float*)d_in[4];
    const float* bs      = (const float*)d_in[5];
    const float* Wg      = (const float*)d_in[6];
    const float* bg      = (const float*)d_in[7];
    const float* g_gamma = (const float*)d_in[8];
    const float* g_beta  = (const float*)d_in[9];
    const float* g_mean  = (const float*)d_in[10];
    const float* g_var   = (const float*)d_in[11];
    const float* Wfi     = (const float*)d_in[12];
    const float* bfi     = (const float*)d_in[13];
    const float* fi_gamma= (const float*)d_in[14];
    const float* fi_beta = (const float*)d_in[15];
    const float* fi_mean = (const float*)d_in[16];
    const float* fi_var  = (const float*)d_in[17];
    const float* Wm      = (const float*)d_in[18];
    const float* bm      = (const float*)d_in[19];
    const float* m_gamma = (const float*)d_in[20];
    const float* m_beta  = (const float*)d_in[21];
    const float* m_mean  = (const float*)d_in[22];
    const float* m_var   = (const float*)d_in[23];
    const float* prelu_a = (const float*)d_in[24];
    float* out = (float*)d_out;

    ushort_t* ws = (ushort_t*)d_ws;
    ushort_t* Wq_h  = ws + 0;         ushort_t* Wq_l  = ws + 65536;
    ushort_t* Ws_h  = ws + 131072;    ushort_t* Ws_l  = ws + 196608;
    ushort_t* Wg_h  = ws + 262144;    ushort_t* Wg_l  = ws + 327680;
    ushort_t* Wfi_h = ws + 393216;    ushort_t* Wfi_l = ws + 524288;
    ushort_t* wm_h  = ws + 655360;    ushort_t* wm_l  = ws + 802816;
    ushort_t* XT_h    = ws + 950272;      // 8,126,464 each
    ushort_t* XT_l    = ws + 9076736;
    ushort_t* xf_tT_h = ws + 17203200;
    ushort_t* xf_tT_l = ws + 25329664;
    ushort_t* zf_tT_h = ws + 33456128;    // 524,288 each
    ushort_t* zf_tT_l = ws + 33980416;
    ushort_t* zf_gT_h = ws + 34504704;
    ushort_t* zf_gT_l = ws + 35028992;
    ushort_t* xf_gT_h = ws + 35553280;
    ushort_t* xf_gT_l = ws + 43679744;
    ushort_t* gat_nf  = ws + 51806208;    // 8,126,464
    ushort_t* eT_h    = ws + 59932672;    // 2,097,152 each
    ushort_t* eT_l    = ws + 62029824;
    ushort_t* PT      = ws + 64126976;    // 32,505,856
    // gx lives INSIDE the PT region: written by attnfi, consumed by conv3x3,
    // then hspa overwrites the region with PT (strictly later in the stream).
    ushort_t* gxT_h   = ws + 64126976;    // 8,921,088
    ushort_t* gxT_l   = ws + 73048064;    // 8,921,088
    ushort_t* zfT_h   = ws + 96632832;    // 524,288 each
    ushort_t* zfT_l   = ws + 97157120;
    float* scsh       = (float*)(ws + 97681408);   // 2176 floats
    ushort_t* zgC_h   = ws + 97685760;    // 524,288 each
    ushort_t* zgC_l   = ws + 98210048;

    const float* sc_q  = scsh + 0,    *sh_q  = scsh + 256;
    const float* sc_s  = scsh + 512,  *sh_s  = scsh + 768;
    const float* sc_g  = scsh + 1024, *sh_g  = scsh + 1280;
    const float* sc_fi = scsh + 1536, *sh_fi = scsh + 1792;
    const float* sc_m  = scsh + 2048, *sh_m  = scsh + 2112;

    prep_all_kernel<<<1857, 256, 0, stream>>>(
        Wq, Ws, Wg, Wfi, Wm,
        bq, bs, bg, g_gamma, g_beta, g_mean, g_var,
        bfi, fi_gamma, fi_beta, fi_mean, fi_var,
        bm, m_gamma, m_beta, m_mean, m_var,
        Wq_h, Wq_l, Ws_h, Ws_l, Wg_h, Wg_l, Wfi_h, Wfi_l, wm_h, wm_l, scsh);

    transpose_in_kernel<<<dim3(31, 8, 32), 256, 0, stream>>>(xf, XT_h, XT_l, 961, 992);
    transpose_in_kernel<<<dim3(2, 8, 32), 256, 0, stream>>>(zf, zfT_h, zfT_l, 49, 64);

    // fused-halves dualconv, 32-row tiles (measured-best variant)
    dualconv_mfma_kernel<<<dim3(32, 31), 256, 0, stream>>>(
        XT_h, XT_l, Wq_h, Wq_l, Wg_h, Wg_l,
        sc_q, sh_q, sc_g, sh_g, 0, 1,
        xf_tT_h, xf_tT_l, xf_gT_h, xf_gT_l,
        nullptr, nullptr, 0, 256, 961, 992, 992);
    dualconv_mfma_kernel<<<dim3(32, 2), 256, 0, stream>>>(
        zfT_h, zfT_l, Ws_h, Ws_l, Wg_h, Wg_l,
        sc_s, sh_s, sc_g, sh_g, 0, 1,
        zf_tT_h, zf_tT_l, zf_gT_h, zf_gT_l,
        zgC_h, zgC_l, 64, 256, 49, 64, 64);

    halo_zero_kernel<<<16, 256, 0, stream>>>(gxT_h, gxT_l);

    attnfi_mfma_kernel<<<dim3(32, 31), 256, 0, stream>>>(
        xf_tT_h, xf_tT_l, zf_tT_h, zf_tT_l, zgC_h, zgC_l,
        xf_gT_h, xf_gT_l, Wfi_h, Wfi_l, sc_fi, sh_fi,
        gxT_h, gxT_l, gat_nf);

    conv3x3_mfma_kernel<<<dim3(32, 16), 256, 0, stream>>>(
        gxT_h, gxT_l, wm_h, wm_l, sc_m, sh_m, prelu_a, eT_h, eT_l);

    hspa_mfma_kernel<<<dim3(32, 31), 512, 0, stream>>>(eT_h, eT_l, PT);

    out_mfma_kernel<<<dim3(32, 16), 256, 0, stream>>>(gat_nf, PT, out);
}

// Round 9
// 545.187 us; speedup vs baseline: 1.2229x; 1.0333x over previous
//
#include <hip/hip_runtime.h>
#include <cstdint>
#include <cstddef>
#include <math.h>

typedef __attribute__((ext_vector_type(8))) short short8;
typedef __attribute__((ext_vector_type(4))) float floatx4;
typedef unsigned short ushort_t;

__device__ __forceinline__ ushort_t f2bf(float x) {
    union { float f; unsigned u; } v; v.f = x;
    unsigned r = v.u + 0x7FFF + ((v.u >> 16) & 1);
    return (ushort_t)(r >> 16);
}
__device__ __forceinline__ float bf2f(ushort_t h) {
    union { unsigned u; float f; } v; v.u = ((unsigned)h) << 16; return v.f;
}
__device__ __forceinline__ void split2(float v, ushort_t& h, ushort_t& l) {
    h = f2bf(v);
    l = f2bf(v - bf2f(h));
}

#define MFMA(a, b, c) __builtin_amdgcn_mfma_f32_16x16x32_bf16((a), (b), (c), 0, 0, 0)

__device__ __forceinline__ void gload_lds16(const void* g, void* l) {
    __builtin_amdgcn_global_load_lds(
        (const __attribute__((address_space(1))) unsigned*)g,
        (__attribute__((address_space(3))) unsigned*)l, 16, 0, 0);
}

// ---------------------------------------------------------------------
// prep_all: all weight hi/lo splits + Wm transpose + BN fold, one launch.
// ---------------------------------------------------------------------
__global__ void prep_all_kernel(
    const float* __restrict__ Wq, const float* __restrict__ Ws,
    const float* __restrict__ Wg, const float* __restrict__ Wfi,
    const float* __restrict__ Wm,
    const float* bq, const float* bs,
    const float* bg, const float* gg, const float* gb, const float* gm, const float* gv,
    const float* bfi, const float* fg, const float* fb, const float* fm, const float* fv,
    const float* bm, const float* mg, const float* mb, const float* mm, const float* mv,
    ushort_t* Wq_h, ushort_t* Wq_l, ushort_t* Ws_h, ushort_t* Ws_l,
    ushort_t* Wg_h, ushort_t* Wg_l, ushort_t* Wfi_h, ushort_t* Wfi_l,
    ushort_t* wm_h, ushort_t* wm_l, float* scsh)
{
    int bid = blockIdx.x, t = threadIdx.x;
    if (bid < 256) {
        int i = bid * 256 + t; ushort_t h, l; split2(Wq[i], h, l); Wq_h[i] = h; Wq_l[i] = l;
    } else if (bid < 512) {
        int i = (bid - 256) * 256 + t; ushort_t h, l; split2(Ws[i], h, l); Ws_h[i] = h; Ws_l[i] = l;
    } else if (bid < 768) {
        int i = (bid - 512) * 256 + t; ushort_t h, l; split2(Wg[i], h, l); Wg_h[i] = h; Wg_l[i] = l;
    } else if (bid < 1280) {
        int i = (bid - 768) * 256 + t; ushort_t h, l; split2(Wfi[i], h, l); Wfi_h[i] = h; Wfi_l[i] = l;
    } else if (bid < 1856) {
        int i = (bid - 1280) * 256 + t;  // [tap][m][c] flattened
        int c = i & 255, m = (i >> 8) & 63, tap = i >> 14;
        ushort_t h, l; split2(Wm[((size_t)m * 256 + c) * 9 + tap], h, l);
        wm_h[i] = h; wm_l[i] = l;
    } else {
        if (t < 256) {
            scsh[t] = 1.f;        scsh[256 + t] = bq[t];
            scsh[512 + t] = 1.f;  scsh[768 + t] = bs[t];
            float s = gg[t] * rsqrtf(gv[t] + 1e-5f);
            scsh[1024 + t] = s;   scsh[1280 + t] = gb[t] + s * (bg[t] - gm[t]);
            float s2 = fg[t] * rsqrtf(fv[t] + 1e-5f);
            scsh[1536 + t] = s2;  scsh[1792 + t] = fb[t] + s2 * (bfi[t] - fm[t]);
            if (t < 64) {
                float s3 = mg[t] * rsqrtf(mv[t] + 1e-5f);
                scsh[2048 + t] = s3; scsh[2112 + t] = mb[t] + s3 * (bm[t] - mm[t]);
            }
        }
    }
}

// halo-only zero of gxT (128 halo rows per batch, hi+lo)
__global__ void halo_zero_kernel(ushort_t* __restrict__ gxh, ushort_t* __restrict__ gxl) {
    int i = blockIdx.x * 256 + threadIdx.x;   // 0..4095
    int b = i >> 7, k = i & 127;
    int r;
    if (k < 33) r = k;
    else if (k < 66) r = 32 * 33 + (k - 33);
    else { int k2 = k - 66; r = ((k2 >> 1) + 1) * 33 + ((k2 & 1) ? 32 : 0); }
    uint4* ph = (uint4*)(gxh + ((size_t)b * 1089 + r) * 256);
    uint4* pl = (uint4*)(gxl + ((size_t)b * 1089 + r) * 256);
    uint4 z = make_uint4(0, 0, 0, 0);
#pragma unroll
    for (int s = 0; s < 32; s++) { ph[s] = z; pl[s] = z; }
}

// fp32 [B][256][Nsrc] -> bf16 hi/lo [B][Npad][256]
// MERGED: blockIdx.x < 31 -> xf (961/992); else (x-31) -> zf (49/64).
__global__ __launch_bounds__(256) void transpose_in_kernel(
    const float* __restrict__ inA, ushort_t* __restrict__ ohA, ushort_t* __restrict__ olA,
    const float* __restrict__ inB, ushort_t* __restrict__ ohB, ushort_t* __restrict__ olB)
{
    int bx = blockIdx.x, b = blockIdx.z;
    int sm = (bx >= 31);
    int Nsrc = sm ? 49 : 961, Npad = sm ? 64 : 992;
    const float* ib = (sm ? inB : inA) + (size_t)b * 256 * Nsrc;
    ushort_t* obh = (sm ? ohB : ohA) + (size_t)b * Npad * 256;
    ushort_t* obl = (sm ? olB : olA) + (size_t)b * Npad * 256;
    __shared__ float tile[32][33];
    int n0 = (sm ? bx - 31 : bx) * 32, c0 = blockIdx.y * 32;
    int tx = threadIdx.x & 31, ty = threadIdx.x >> 5;
#pragma unroll
    for (int r = 0; r < 4; r++) {
        int c = c0 + ty + r * 8, n = n0 + tx;
        tile[ty + r * 8][tx] = (n < Nsrc) ? ib[(size_t)c * Nsrc + n] : 0.f;
    }
    __syncthreads();
#pragma unroll
    for (int r = 0; r < 4; r++) {
        int n = n0 + ty + r * 8, c = c0 + tx;
        if (n < Nsrc) {
            ushort_t h, l; split2(tile[tx][ty + r * 8], h, l);
            obh[(size_t)n * 256 + c] = h;
            obl[(size_t)n * 256 + c] = l;
        }
    }
}

// ---------------------------------------------------------------------
// dual conv1x1, FUSED halves + 32-row LDS-staged B. MERGED big/small:
// blockIdx.y < 31 -> xf path; else (y-31) -> zf path (fills CU tail).
// grid (B, 33).
// ---------------------------------------------------------------------
__global__ __launch_bounds__(256, 2) void dualconv_mfma_kernel(
    const ushort_t* __restrict__ XAh, const ushort_t* __restrict__ XAl,
    const ushort_t* __restrict__ XBh, const ushort_t* __restrict__ XBl,
    const ushort_t* __restrict__ Wqh, const ushort_t* __restrict__ Wql,
    const ushort_t* __restrict__ Wsh, const ushort_t* __restrict__ Wsl,
    const ushort_t* __restrict__ Wgh, const ushort_t* __restrict__ Wgl,
    const float* __restrict__ scsh,
    ushort_t* __restrict__ xtA_h, ushort_t* __restrict__ xtA_l,
    ushort_t* __restrict__ xgA_h, ushort_t* __restrict__ xgA_l,
    ushort_t* __restrict__ ztB_h, ushort_t* __restrict__ ztB_l,
    ushort_t* __restrict__ zgB_h, ushort_t* __restrict__ zgB_l,
    ushort_t* __restrict__ zgC_h, ushort_t* __restrict__ zgC_l)
{
    const int K = 256, cpitch = 64;
    __shared__ ushort_t Bs[16384];   // 32 KB: hi rows @byte 0, lo rows @byte 16384
    int b = blockIdx.x;
    int yy = blockIdx.y;
    int smj = (yy >= 31);
    int n0 = (smj ? yy - 31 : yy) * 32;
    int NpadIn = smj ? 64 : 992;        // NpadOut == NpadIn for both jobs
    int Nvalid = smj ? 49 : 961;
    const ushort_t* Xbh = (smj ? XBh : XAh) + (size_t)b * NpadIn * K;
    const ushort_t* Xbl = (smj ? XBl : XAl) + (size_t)b * NpadIn * K;
    int tid = threadIdx.x, w = tid >> 6, l = tid & 63, lc = l & 15, q = l >> 4;
    int m0 = w * 64;

    // ---- stage B tile (swizzle: in-row byte ^= (row&7)<<4, folded into src) ----
#pragma unroll
    for (int r = 0; r < 8; r++) {
        int d = r * 4096 + w * 1024 + l * 16;      // linear byte in 32KB region
        int seg = d >> 14;                          // 0 = hi, 1 = lo
        int dr = d & 16383;
        int row = dr >> 9;
        int inrow = (dr & 511) ^ ((row & 7) << 4);
        int srow = n0 + row; if (srow > NpadIn - 1) srow = NpadIn - 1;
        const ushort_t* src = (seg ? Xbl : Xbh) + (size_t)srow * K + (inrow >> 1);
        char* dst = (char*)Bs + (r * 4096 + w * 1024);
        gload_lds16(src, dst);
    }
    __syncthreads();

#define DC_LOADA(K0, AH, AL) do { \
    _Pragma("unroll") \
    for (int mt_ = 0; mt_ < 4; mt_++) { \
        size_t off_ = (size_t)(m0 + mt_ * 16 + lc) * K + (K0) + q * 8; \
        AH[mt_] = *(const short8*)(Wh + off_); \
        AL[mt_] = *(const short8*)(Wl + off_); \
    } \
} while (0)
#define DC_LDSB(K0, BH, BL) do { \
    _Pragma("unroll") \
    for (int jt_ = 0; jt_ < 2; jt_++) { \
        int row_ = jt_ * 16 + lc; \
        int koff_ = (((K0) + q * 8) * 2) ^ ((row_ & 7) << 4); \
        BH[jt_] = *(const short8*)((const char*)Bs + row_ * 512 + koff_); \
        BL[jt_] = *(const short8*)((const char*)Bs + 16384 + row_ * 512 + koff_); \
    } \
} while (0)
#define DC_MFMA(AH, AL, BH, BL) do { \
    _Pragma("unroll") \
    for (int mt_ = 0; mt_ < 4; mt_++) \
    _Pragma("unroll") \
    for (int jt_ = 0; jt_ < 2; jt_++) { \
        acc[mt_][jt_] = MFMA(AH[mt_], BH[jt_], acc[mt_][jt_]); \
        acc[mt_][jt_] = MFMA(AH[mt_], BL[jt_], acc[mt_][jt_]); \
        acc[mt_][jt_] = MFMA(AL[mt_], BH[jt_], acc[mt_][jt_]); \
    } \
} while (0)

    for (int half = 0; half < 2; half++) {
        const ushort_t* Wh = half ? Wgh : (smj ? Wsh : Wqh);
        const ushort_t* Wl = half ? Wgl : (smj ? Wsl : Wql);
        const float* sc = half ? scsh + 1024 : (smj ? scsh + 512 : scsh + 0);
        const float* sh = half ? scsh + 1280 : (smj ? scsh + 768 : scsh + 256);
        int relu = half;
        ushort_t* Obh = (half ? (smj ? zgB_h : xgA_h) : (smj ? ztB_h : xtA_h))
                        + (size_t)b * NpadIn * 256;
        ushort_t* Obl = (half ? (smj ? zgB_l : xgA_l) : (smj ? ztB_l : xtA_l))
                        + (size_t)b * NpadIn * 256;

        floatx4 acc[4][2];
#pragma unroll
        for (int i = 0; i < 4; i++)
#pragma unroll
            for (int j = 0; j < 2; j++) acc[i][j] = (floatx4){0.f, 0.f, 0.f, 0.f};

        short8 ah0[4], al0[4], ah1[4], al1[4], bh[2], bl[2];
        DC_LOADA(0, ah0, al0);
        for (int k0 = 0; k0 < K; k0 += 64) {
            DC_LOADA(k0 + 32, ah1, al1);
            DC_LDSB(k0, bh, bl);
            DC_MFMA(ah0, al0, bh, bl);
            if (k0 + 64 < K) DC_LOADA(k0 + 64, ah0, al0);
            DC_LDSB(k0 + 32, bh, bl);
            DC_MFMA(ah1, al1, bh, bl);
        }

#pragma unroll
        for (int mt = 0; mt < 4; mt++) {
            int mb = m0 + mt * 16 + q * 4;
            float s0 = sc[mb], s1 = sc[mb + 1], s2 = sc[mb + 2], s3 = sc[mb + 3];
            float h0 = sh[mb], h1 = sh[mb + 1], h2 = sh[mb + 2], h3 = sh[mb + 3];
#pragma unroll
            for (int jt = 0; jt < 2; jt++) {
                int n = n0 + jt * 16 + lc;
                if (n >= Nvalid) continue;
                float v0 = acc[mt][jt][0] * s0 + h0;
                float v1 = acc[mt][jt][1] * s1 + h1;
                float v2 = acc[mt][jt][2] * s2 + h2;
                float v3 = acc[mt][jt][3] * s3 + h3;
                if (relu) { v0 = fmaxf(v0, 0.f); v1 = fmaxf(v1, 0.f); v2 = fmaxf(v2, 0.f); v3 = fmaxf(v3, 0.f); }
                ushort_t e0, f0, e1, f1, e2, f2, e3, f3;
                split2(v0, e0, f0); split2(v1, e1, f1); split2(v2, e2, f2); split2(v3, e3, f3);
                *(ushort4*)(Obh + (size_t)n * 256 + mb) = make_ushort4(e0, e1, e2, e3);
                *(ushort4*)(Obl + (size_t)n * 256 + mb) = make_ushort4(f0, f1, f2, f3);
                if (half && smj) {
                    zgC_h[((size_t)b * 256 + mb + 0) * cpitch + n] = e0;
                    zgC_h[((size_t)b * 256 + mb + 1) * cpitch + n] = e1;
                    zgC_h[((size_t)b * 256 + mb + 2) * cpitch + n] = e2;
                    zgC_h[((size_t)b * 256 + mb + 3) * cpitch + n] = e3;
                    zgC_l[((size_t)b * 256 + mb + 0) * cpitch + n] = f0;
                    zgC_l[((size_t)b * 256 + mb + 1) * cpitch + n] = f1;
                    zgC_l[((size_t)b * 256 + mb + 2) * cpitch + n] = f2;
                    zgC_l[((size_t)b * 256 + mb + 3) * cpitch + n] = f3;
                }
            }
        }
    }
#undef DC_LOADA
#undef DC_LDSB
#undef DC_MFMA
}

// ---------------------------------------------------------------------
// FUSED attention + fi conv. grid (B, 31), 32 n-rows per block, 4 waves.
// LDS = 8 KB SM (sim scores; softmax packs bf16 hi/lo attn weights back
// into the same rows via register buffering) + 32 KB EM = 40960 B exactly
// -> 4 blocks/CU (was 50688 -> 3). Same MFMA terms as before.
// ---------------------------------------------------------------------
__global__ __launch_bounds__(256, 4) void attnfi_mfma_kernel(
    const ushort_t* __restrict__ xth, const ushort_t* __restrict__ xtl,
    const ushort_t* __restrict__ zth, const ushort_t* __restrict__ ztl,
    const ushort_t* __restrict__ zgh, const ushort_t* __restrict__ zgl,
    const ushort_t* __restrict__ Gh, const ushort_t* __restrict__ Gl,
    const ushort_t* __restrict__ Wh, const ushort_t* __restrict__ Wl,
    const float* __restrict__ sc, const float* __restrict__ sh,
    ushort_t* __restrict__ gxh, ushort_t* __restrict__ gxl,
    ushort_t* __restrict__ gat_nf)
{
    __shared__ float SM[32][64];      // 8 KB: sim scores -> packed attn weights
    __shared__ ushort_t EM[16384];    // 32 KB staged B (emb, then xf_g)

    int b = blockIdx.x, nb0 = blockIdx.y * 32;
    int tid = threadIdx.x, w = tid >> 6, l = tid & 63, lc = l & 15, q = l >> 4;
    const ushort_t* xhb = xth + (size_t)b * 992 * 256;
    const ushort_t* xlb = xtl + (size_t)b * 992 * 256;
    const ushort_t* zhb = zth + (size_t)b * 64 * 256;
    const ushort_t* zlb = ztl + (size_t)b * 64 * 256;
    const ushort_t* ghb = zgh + (size_t)b * 256 * 64;
    const ushort_t* glb = zgl + (size_t)b * 256 * 64;
    const ushort_t* Gbh = Gh + (size_t)b * 992 * 256;
    const ushort_t* Gbl = Gl + (size_t)b * 992 * 256;
    ushort_t* gxhb = gxh + (size_t)b * 1089 * 256;
    ushort_t* gxlb = gxl + (size_t)b * 1089 * 256;
    ushort_t* gn = gat_nf + (size_t)b * 256 * 992;
    int m0 = w * 64;

    // ---- P1: sim = xf_t . zf_t^T  (wave: row-group w>>1, ct pair (w&1)*2) ----
    {
        int rg = w >> 1, c2 = (w & 1) * 2;
        size_t arow = (size_t)(nb0 + rg * 16 + lc) * 256;
        size_t brow0 = (size_t)(c2 * 16 + lc) * 256;
        size_t brow1 = (size_t)((c2 + 1) * 16 + lc) * 256;
        floatx4 s0 = (floatx4){0.f, 0.f, 0.f, 0.f};
        floatx4 s1 = (floatx4){0.f, 0.f, 0.f, 0.f};
        for (int k0 = 0; k0 < 256; k0 += 32) {
            short8 ah = *(const short8*)(xhb + arow + k0 + q * 8);
            short8 al = *(const short8*)(xlb + arow + k0 + q * 8);
            short8 b0h = *(const short8*)(zhb + brow0 + k0 + q * 8);
            short8 b0l = *(const short8*)(zlb + brow0 + k0 + q * 8);
            short8 b1h = *(const short8*)(zhb + brow1 + k0 + q * 8);
            short8 b1l = *(const short8*)(zlb + brow1 + k0 + q * 8);
            s0 = MFMA(ah, b0h, s0); s0 = MFMA(ah, b0l, s0); s0 = MFMA(al, b0h, s0);
            s1 = MFMA(ah, b1h, s1); s1 = MFMA(ah, b1l, s1); s1 = MFMA(al, b1h, s1);
        }
#pragma unroll
        for (int r = 0; r < 4; r++) {
            SM[rg * 16 + q * 4 + r][c2 * 16 + lc] = s0[r];
            SM[rg * 16 + q * 4 + r][(c2 + 1) * 16 + lc] = s1[r];
        }
    }
    __syncthreads();

    // ---- softmax over m (49 valid); pack bf16 hi/lo back into SM rows.
    // 2 threads per row; each buffers its half in regs BEFORE any write
    // (wave-lockstep makes read-phase precede write-phase for all lanes).
    if (tid < 64) {
        int row = tid & 31, hf = tid >> 5;
        int mcnt = hf ? 24 : 25;          // hf0: m 0..24, hf1: m 25..48
        float v[25];
        float mx = -INFINITY;
#pragma unroll
        for (int m = 0; m < 25; m++) {
            float x = (m < mcnt) ? SM[row][(hf ? 25 : 0) + m] : -INFINITY;
            v[m] = x; mx = fmaxf(mx, x);
        }
        mx = fmaxf(mx, __shfl_xor(mx, 32));
        float sum = 0.f;
#pragma unroll
        for (int m = 0; m < 25; m++) {
            float e = (m < mcnt) ? __expf(v[m] - mx) : 0.f;
            v[m] = e; sum += e;
        }
        sum += __shfl_xor(sum, 32);
        float inv = 1.f / sum;
        ushort_t* rowp = (ushort_t*)&SM[row][0];   // hi at [0..63], lo at [64..127]
        if (hf == 0) {
#pragma unroll
            for (int m = 0; m < 25; m++) {
                ushort_t hh, ll; split2(v[m] * inv, hh, ll);
                rowp[m] = hh; rowp[64 + m] = ll;
            }
        } else {
#pragma unroll
            for (int m = 0; m < 39; m++) {        // slots 25..63 (zeros past 48)
                float vv = (m < 24) ? v[m] * inv : 0.f;
                ushort_t hh, ll; split2(vv, hh, ll);
                rowp[25 + m] = hh; rowp[89 + m] = ll;
            }
        }
    }
    __syncthreads();

    // ---- P2: emb = zg . attn -> EM (swizzled bf16 hi/lo, rows n) ----
#pragma unroll
    for (int rg = 0; rg < 2; rg++) {
        const ushort_t* rowp = (const ushort_t*)&SM[rg * 16 + lc][0];
        short8 pah0 = *(const short8*)(rowp + q * 8);
        short8 pal0 = *(const short8*)(rowp + 64 + q * 8);
        short8 pah1 = *(const short8*)(rowp + 32 + q * 8);
        short8 pal1 = *(const short8*)(rowp + 96 + q * 8);
#pragma unroll
        for (int t = 0; t < 4; t++) {
            int ct = w * 4 + t;
            size_t brow = (size_t)(ct * 16 + lc) * 64;
            short8 bh0 = *(const short8*)(ghb + brow + q * 8);
            short8 bl0 = *(const short8*)(glb + brow + q * 8);
            short8 bh1 = *(const short8*)(ghb + brow + 32 + q * 8);
            short8 bl1 = *(const short8*)(glb + brow + 32 + q * 8);
            floatx4 a = (floatx4){0.f, 0.f, 0.f, 0.f};
            a = MFMA(pah0, bh0, a); a = MFMA(pah0, bl0, a); a = MFMA(pal0, bh0, a);
            a = MFMA(pah1, bh1, a); a = MFMA(pah1, bl1, a); a = MFMA(pal1, bh1, a);
            int cc = ct * 16 + lc;
#pragma unroll
            for (int r = 0; r < 4; r++) {
                int n = rg * 16 + q * 4 + r;
                int off = n * 512 + ((cc * 2) ^ ((n & 7) << 4));
                ushort_t hh, ll; split2(a[r], hh, ll);
                *(ushort_t*)((char*)EM + off) = hh;
                *(ushort_t*)((char*)EM + 16384 + off) = ll;
            }
        }
    }
    __syncthreads();

    // ---- P3: fi conv, phase A (k=0..255, B=emb) then B (k>=256, B=xf_g) ----
#define AF_LOADA(K0, AH, AL) do { \
    _Pragma("unroll") \
    for (int mt_ = 0; mt_ < 4; mt_++) { \
        size_t off_ = (size_t)(m0 + mt_ * 16 + lc) * 512 + (K0) + q * 8; \
        AH[mt_] = *(const short8*)(Wh + off_); \
        AL[mt_] = *(const short8*)(Wl + off_); \
    } \
} while (0)
#define AF_LDSB(K0, BH, BL) do { \
    _Pragma("unroll") \
    for (int jt_ = 0; jt_ < 2; jt_++) { \
        int row_ = jt_ * 16 + lc; \
        int koff_ = (((K0) + q * 8) * 2) ^ ((row_ & 7) << 4); \
        BH[jt_] = *(const short8*)((const char*)EM + row_ * 512 + koff_); \
        BL[jt_] = *(const short8*)((const char*)EM + 16384 + row_ * 512 + koff_); \
    } \
} while (0)
#define AF_MFMA(AH, AL, BH, BL) do { \
    _Pragma("unroll") \
    for (int mt_ = 0; mt_ < 4; mt_++) \
    _Pragma("unroll") \
    for (int jt_ = 0; jt_ < 2; jt_++) { \
        acc[mt_][jt_] = MFMA(AH[mt_], BH[jt_], acc[mt_][jt_]); \
        acc[mt_][jt_] = MFMA(AH[mt_], BL[jt_], acc[mt_][jt_]); \
        acc[mt_][jt_] = MFMA(AL[mt_], BH[jt_], acc[mt_][jt_]); \
    } \
} while (0)

    floatx4 acc[4][2];
#pragma unroll
    for (int i = 0; i < 4; i++)
#pragma unroll
        for (int j = 0; j < 2; j++) acc[i][j] = (floatx4){0.f, 0.f, 0.f, 0.f};

    {
        short8 ah0[4], al0[4], ah1[4], al1[4], bh[2], bl[2];
        AF_LOADA(0, ah0, al0);
        for (int kk = 0; kk < 256; kk += 64) {
            AF_LOADA(kk + 32, ah1, al1);
            AF_LDSB(kk, bh, bl);
            AF_MFMA(ah0, al0, bh, bl);
            if (kk + 64 < 256) AF_LOADA(kk + 64, ah0, al0);
            AF_LDSB(kk + 32, bh, bl);
            AF_MFMA(ah1, al1, bh, bl);
        }
    }
    __syncthreads();            // all waves done reading emb from EM

    // stage xf_g (32 rows, swizzled via pre-swizzled global src) into EM
#pragma unroll
    for (int r = 0; r < 8; r++) {
        int d = r * 4096 + w * 1024 + l * 16;
        int seg = d >> 14;
        int dr = d & 16383;
        int row = dr >> 9;
        int inrow = (dr & 511) ^ ((row & 7) << 4);
        int srow = nb0 + row; if (srow > 991) srow = 991;
        const ushort_t* src = (seg ? Gbl : Gbh) + (size_t)srow * 256 + (inrow >> 1);
        gload_lds16(src, (char*)EM + d);
    }
    __syncthreads();            // staging drained

    {
        short8 ah0[4], al0[4], ah1[4], al1[4], bh[2], bl[2];
        AF_LOADA(256, ah0, al0);
        for (int kk = 0; kk < 256; kk += 64) {
            AF_LOADA(256 + kk + 32, ah1, al1);
            AF_LDSB(kk, bh, bl);
            AF_MFMA(ah0, al0, bh, bl);
            if (kk + 64 < 256) AF_LOADA(256 + kk + 64, ah0, al0);
            AF_LDSB(kk + 32, bh, bl);
            AF_MFMA(ah1, al1, bh, bl);
        }
    }
#undef AF_LOADA
#undef AF_LDSB
#undef AF_MFMA

    // ---- epilogue: BN+relu, write gx (halo layout) + gat_nf ----
#pragma unroll
    for (int mt = 0; mt < 4; mt++) {
        int mb = m0 + mt * 16 + q * 4;
        float s0 = sc[mb], s1 = sc[mb + 1], s2 = sc[mb + 2], s3 = sc[mb + 3];
        float h0 = sh[mb], h1 = sh[mb + 1], h2 = sh[mb + 2], h3 = sh[mb + 3];
#pragma unroll
        for (int jt = 0; jt < 2; jt++) {
            int n = nb0 + jt * 16 + lc;
            if (n >= 961) continue;
            float v0 = fmaxf(acc[mt][jt][0] * s0 + h0, 0.f);
            float v1 = fmaxf(acc[mt][jt][1] * s1 + h1, 0.f);
            float v2 = fmaxf(acc[mt][jt][2] * s2 + h2, 0.f);
            float v3 = fmaxf(acc[mt][jt][3] * s3 + h3, 0.f);
            ushort_t a0, b0, a1, b1, a2, b2, a3, b3;
            split2(v0, a0, b0); split2(v1, a1, b1); split2(v2, a2, b2); split2(v3, a3, b3);
            int hh = n / 31, ww2 = n - hh * 31;
            int row = (hh + 1) * 33 + (ww2 + 1);
            *(ushort4*)(gxhb + (size_t)row * 256 + mb) = make_ushort4(a0, a1, a2, a3);
            *(ushort4*)(gxlb + (size_t)row * 256 + mb) = make_ushort4(b0, b1, b2, b3);
            gn[(size_t)(mb + 0) * 992 + n] = a0;
            gn[(size_t)(mb + 1) * 992 + n] = a1;
            gn[(size_t)(mb + 2) * 992 + n] = a2;
            gn[(size_t)(mb + 3) * 992 + n] = a3;
        }
    }
}

// ---------------------------------------------------------------------
// conv3x3 split-K: block = 4 waves over ONE 64m x 64j tile, 72 (tap,k0)
// steps split 18/wave (k0-major, tap-fast), 1-deep register double-buffer,
// partials reduced in LDS in two 32j phases. grid (B, 16) batch-major.
// ---------------------------------------------------------------------
__global__ __launch_bounds__(256, 2) void conv3x3_mfma_kernel(
    const ushort_t* __restrict__ gxh, const ushort_t* __restrict__ gxl,
    const ushort_t* __restrict__ wmh, const ushort_t* __restrict__ wml,
    const float* __restrict__ sc, const float* __restrict__ sh,
    const float* __restrict__ prelu_a,
    ushort_t* __restrict__ eh, ushort_t* __restrict__ el)
{
    __shared__ float Sp[4][2048];   // 4 waves x (64m x 32j) partials, 32 KB
    int b = blockIdx.x;
    const ushort_t* gxhb = gxh + (size_t)b * 1089 * 256;
    const ushort_t* gxlb = gxl + (size_t)b * 1089 * 256;
    ushort_t* ebh = eh + (size_t)b * 1024 * 64;
    ushort_t* ebl = el + (size_t)b * 1024 * 64;
    int tid = threadIdx.x, w = tid >> 6, l = tid & 63, lc = l & 15, q = l >> 4;
    int j0 = blockIdx.y * 64;

    int base[4];
#pragma unroll
    for (int jt = 0; jt < 4; jt++) {
        int j = j0 + jt * 16 + lc; if (j > 960) j = 960;
        int hh = j / 31, ww2 = j - hh * 31;
        base[jt] = (hh + 1) * 33 + (ww2 + 1);
    }

    floatx4 acc[4][4];
#pragma unroll
    for (int i = 0; i < 4; i++)
#pragma unroll
        for (int j = 0; j < 4; j++) acc[i][j] = (floatx4){0.f, 0.f, 0.f, 0.f};

#define C3_LOAD(SL, AH, AL, BH, BL) do { \
    int sl_ = (SL); \
    int tap_ = (sl_ >= 9) ? sl_ - 9 : sl_; \
    int k0_ = (w * 2 + ((sl_ >= 9) ? 1 : 0)) * 32; \
    int doff_ = (tap_ / 3 - 1) * 33 + (tap_ % 3 - 1); \
    const ushort_t* wth_ = wmh + tap_ * 16384; \
    const ushort_t* wtl_ = wml + tap_ * 16384; \
    _Pragma("unroll") \
    for (int mt_ = 0; mt_ < 4; mt_++) { \
        size_t off_ = (size_t)(mt_ * 16 + lc) * 256 + k0_ + q * 8; \
        AH[mt_] = *(const short8*)(wth_ + off_); \
        AL[mt_] = *(const short8*)(wtl_ + off_); \
    } \
    _Pragma("unroll") \
    for (int jt_ = 0; jt_ < 4; jt_++) { \
        size_t off_ = (size_t)(base[jt_] + doff_) * 256 + k0_ + q * 8; \
        BH[jt_] = *(const short8*)(gxhb + off_); \
        BL[jt_] = *(const short8*)(gxlb + off_); \
    } \
} while (0)
#define C3_MFMA(AH, AL, BH, BL) do { \
    _Pragma("unroll") \
    for (int mt_ = 0; mt_ < 4; mt_++) \
    _Pragma("unroll") \
    for (int jt_ = 0; jt_ < 4; jt_++) { \
        acc[mt_][jt_] = MFMA(AH[mt_], BH[jt_], acc[mt_][jt_]); \
        acc[mt_][jt_] = MFMA(AH[mt_], BL[jt_], acc[mt_][jt_]); \
        acc[mt_][jt_] = MFMA(AL[mt_], BH[jt_], acc[mt_][jt_]); \
    } \
} while (0)

    short8 A0h[4], A0l[4], B0h[4], B0l[4];
    short8 A1h[4], A1l[4], B1h[4], B1l[4];
    C3_LOAD(0, A0h, A0l, B0h, B0l);
#pragma unroll
    for (int it = 0; it < 9; it++) {
        C3_LOAD(it * 2 + 1, A1h, A1l, B1h, B1l);
        C3_MFMA(A0h, A0l, B0h, B0l);
        if (it < 8) C3_LOAD(it * 2 + 2, A0h, A0l, B0h, B0l);
        C3_MFMA(A1h, A1l, B1h, B1l);
    }
#undef C3_LOAD
#undef C3_MFMA

    float pa = prelu_a[0];
#pragma unroll
    for (int ph = 0; ph < 2; ph++) {
        __syncthreads();
#pragma unroll
        for (int mt = 0; mt < 4; mt++)
#pragma unroll
            for (int jt = 0; jt < 2; jt++)
#pragma unroll
                for (int r = 0; r < 4; r++)
                    Sp[w][(mt * 16 + q * 4 + r) * 32 + jt * 16 + lc] = acc[mt][ph * 2 + jt][r];
        __syncthreads();
#pragma unroll
        for (int gi = 0; gi < 2; gi++) {
            int g = tid + gi * 256;
            int j = g & 31, mg = g >> 5;
            int m = mg * 4;
            int jj = j0 + ph * 32 + j;
            if (jj >= 961) continue;
            float v[4];
#pragma unroll
            for (int i = 0; i < 4; i++) {
                int idx = (m + i) * 32 + j;
                v[i] = Sp[0][idx] + Sp[1][idx] + Sp[2][idx] + Sp[3][idx];
                v[i] = v[i] * sc[m + i] + sh[m + i];
                v[i] = v[i] >= 0.f ? v[i] : pa * v[i];
            }
            ushort_t a0, b0, a1, b1, a2, b2, a3, b3;
            split2(v[0], a0, b0); split2(v[1], a1, b1);
            split2(v[2], a2, b2); split2(v[3], a3, b3);
            *(ushort4*)(ebh + (size_t)jj * 64 + m) = make_ushort4(a0, a1, a2, a3);
            *(ushort4*)(ebl + (size_t)jj * 64 + m) = make_ushort4(b0, b1, b2, b3);
        }
    }
}

// ---------------------------------------------------------------------
// HSPA: S = e^T e -> sparsemax (Michelot) -> P^T bf16.
// Block owns 32 rows (2 groups of 16): GEMM keeps BOTH groups' accs in
// registers (acc[2][8], static idx) with 1-deep b-prefetch over the 61
// j-tiles; groups then dump->Michelot->PT-write sequentially through one
// 63 KB S buffer. grid (B, 31).
// ---------------------------------------------------------------------
__global__ __launch_bounds__(512) void hspa_mfma_kernel(
    const ushort_t* __restrict__ eh, const ushort_t* __restrict__ el,
    ushort_t* __restrict__ PT)
{
    const int PITCH = 978;
    __shared__ float S[16 * 978];
    int b = blockIdx.x, nb = blockIdx.y;
    const ushort_t* ebh = eh + (size_t)b * 1024 * 64;
    const ushort_t* ebl = el + (size_t)b * 1024 * 64;
    ushort_t* Pb = PT + (size_t)b * 1024 * 992;
    int tid = threadIdx.x, w = tid >> 6, l = tid & 63, lc = l & 15, q = l >> 4;
    int n0 = nb * 32;

    // A fragments: 2 row-groups x 2 k-halves
    short8 Ah[2][2], Al[2][2];
#pragma unroll
    for (int g = 0; g < 2; g++)
#pragma unroll
        for (int kh = 0; kh < 2; kh++) {
            size_t off = (size_t)(n0 + g * 16 + lc) * 64 + kh * 32 + q * 8;
            Ah[g][kh] = *(const short8*)(ebh + off);
            Al[g][kh] = *(const short8*)(ebl + off);
        }

    floatx4 acc[2][8];
#pragma unroll
    for (int g = 0; g < 2; g++)
#pragma unroll
        for (int s = 0; s < 8; s++) acc[g][s] = (floatx4){0.f, 0.f, 0.f, 0.f};

#define HS_LOADB(SLOT, BH0, BL0, BH1, BL1) do { \
    int jt_ = w + (SLOT) * 8; if (jt_ > 60) jt_ = 60; \
    size_t o_ = (size_t)(jt_ * 16 + lc) * 64 + q * 8; \
    BH0 = *(const short8*)(ebh + o_); \
    BL0 = *(const short8*)(ebl + o_); \
    BH1 = *(const short8*)(ebh + o_ + 32); \
    BL1 = *(const short8*)(ebl + o_ + 32); \
} while (0)

    {
        short8 b0h[2], b0l[2], b1h[2], b1l[2];
        HS_LOADB(0, b0h[0], b0l[0], b1h[0], b1l[0]);
#pragma unroll
        for (int s = 0; s < 8; s++) {
            const int cur = s & 1, nxt = cur ^ 1;
            if (s < 7) HS_LOADB(s + 1, b0h[nxt], b0l[nxt], b1h[nxt], b1l[nxt]);
#pragma unroll
            for (int g = 0; g < 2; g++) {
                floatx4 a = acc[g][s];
                a = MFMA(Ah[g][0], b0h[cur], a);
                a = MFMA(Ah[g][0], b0l[cur], a);
                a = MFMA(Al[g][0], b0h[cur], a);
                a = MFMA(Ah[g][1], b1h[cur], a);
                a = MFMA(Ah[g][1], b1l[cur], a);
                a = MFMA(Al[g][1], b1h[cur], a);
                acc[g][s] = a;
            }
        }
    }
#undef HS_LOADB

#pragma unroll
    for (int g = 0; g < 2; g++) {
        if (g) __syncthreads();           // prior group's PT-write done reading S
#pragma unroll
        for (int s = 0; s < 8; s++) {
            int jt = w + s * 8;
            if (jt < 61) {
                int j = jt * 16 + lc;
#pragma unroll
                for (int r = 0; r < 4; r++)
                    S[(q * 4 + r) * PITCH + j] = acc[g][s][r];
            }
        }
        __syncthreads();

        int r0 = w * 2, r1 = w * 2 + 1;
        float sv0[16], sv1[16];
        float mx0 = -INFINITY, mx1 = -INFINITY;
#pragma unroll
        for (int t = 0; t < 16; t++) {
            int j = l + t * 64;
            float s0 = (j < 961) ? S[r0 * PITCH + j] : -INFINITY;
            float s1 = (j < 961) ? S[r1 * PITCH + j] : -INFINITY;
            sv0[t] = s0; sv1[t] = s1;
            mx0 = fmaxf(mx0, s0); mx1 = fmaxf(mx1, s1);
        }
        for (int off = 32; off; off >>= 1) {
            mx0 = fmaxf(mx0, __shfl_xor(mx0, off));
            mx1 = fmaxf(mx1, __shfl_xor(mx1, off));
        }
#pragma unroll
        for (int t = 0; t < 16; t++) { sv0[t] -= mx0; sv1[t] -= mx1; }

        float tau0 = -1.f, tau1 = -1.f;
        for (int it = 0; it < 16; it++) {
            float s0 = 0.f, c0 = 0.f, s1 = 0.f, c1 = 0.f;
#pragma unroll
            for (int t = 0; t < 16; t++) {
                if (sv0[t] > tau0) { s0 += sv0[t]; c0 += 1.f; }
                if (sv1[t] > tau1) { s1 += sv1[t]; c1 += 1.f; }
            }
            for (int off = 32; off; off >>= 1) {
                s0 += __shfl_xor(s0, off); c0 += __shfl_xor(c0, off);
                s1 += __shfl_xor(s1, off); c1 += __shfl_xor(c1, off);
            }
            float nt0 = (s0 - 1.f) / c0;
            float nt1 = (s1 - 1.f) / c1;
            bool conv = (nt0 == tau0) && (nt1 == tau1);
            tau0 = nt0; tau1 = nt1;
            if (conv) break;
        }
#pragma unroll
        for (int t = 0; t < 16; t++) {
            int j = l + t * 64;
            if (j < 976) {
                S[r0 * PITCH + j] = (j < 961) ? fmaxf(sv0[t] - tau0, 0.f) : 0.f;
                S[r1 * PITCH + j] = (j < 961) ? fmaxf(sv1[t] - tau1, 0.f) : 0.f;
            }
        }
        __syncthreads();

        int nbase = n0 + g * 16;
        if (nbase < 976) {
            for (int j = tid; j < 976; j += 512) {
                union { ushort_t u[8]; uint4 v; } p0, p1;
#pragma unroll
                for (int r = 0; r < 8; r++)  p0.u[r] = f2bf(S[r * PITCH + j]);
#pragma unroll
                for (int r = 0; r < 8; r++)  p1.u[r] = f2bf(S[(8 + r) * PITCH + j]);
                ushort_t* dst = Pb + (size_t)j * 992 + nbase;
                *(uint4*)(dst) = p0.v;
                *(uint4*)(dst + 8) = p1.v;
            }
        }
    }
}

// ---------------------------------------------------------------------
// out = gat @ P + gat. grid (B, 16) batch-major.
// ---------------------------------------------------------------------
__global__ __launch_bounds__(256, 2) void out_mfma_kernel(
    const ushort_t* __restrict__ gat_nf, const ushort_t* __restrict__ PT,
    float* __restrict__ out)
{
    int b = blockIdx.x, jb = blockIdx.y;
    const ushort_t* gb = gat_nf + (size_t)b * 256 * 992;
    const ushort_t* Pb = PT + (size_t)b * 1024 * 992;
    float* ob = out + (size_t)b * 256 * 961;
    int tid = threadIdx.x, w = tid >> 6, l = tid & 63, lc = l & 15, q = l >> 4;
    int m0 = w * 64, j0 = jb * 64;

    floatx4 acc[4][4];
#pragma unroll
    for (int i = 0; i < 4; i++)
#pragma unroll
        for (int j = 0; j < 4; j++) acc[i][j] = (floatx4){0.f, 0.f, 0.f, 0.f};

#define OUT_LOAD(K0, AA, BB) do { \
    _Pragma("unroll") \
    for (int mt_ = 0; mt_ < 4; mt_++) \
        AA[mt_] = *(const short8*)(gb + (size_t)(m0 + mt_ * 16 + lc) * 992 + (K0) + q * 8); \
    _Pragma("unroll") \
    for (int jt_ = 0; jt_ < 4; jt_++) \
        BB[jt_] = *(const short8*)(Pb + (size_t)(j0 + jt_ * 16 + lc) * 992 + (K0) + q * 8); \
} while (0)
#define OUT_MFMA(AA, BB) do { \
    _Pragma("unroll") \
    for (int mt_ = 0; mt_ < 4; mt_++) \
    _Pragma("unroll") \
    for (int jt_ = 0; jt_ < 4; jt_++) \
        acc[mt_][jt_] = MFMA(AA[mt_], BB[jt_], acc[mt_][jt_]); \
} while (0)

    short8 a0[4], b0[4], a1[4], b1[4];
    OUT_LOAD(0, a0, b0);
    for (int k0 = 0; k0 < 960; k0 += 64) {
        OUT_LOAD(k0 + 32, a1, b1);
        OUT_MFMA(a0, b0);
        OUT_LOAD(k0 + 64, a0, b0);
        OUT_MFMA(a1, b1);
    }
    OUT_MFMA(a0, b0);   // k0 = 960
#undef OUT_LOAD
#undef OUT_MFMA

#pragma unroll
    for (int mt = 0; mt < 4; mt++) {
        int mb = m0 + mt * 16 + q * 4;
#pragma unroll
        for (int jt = 0; jt < 4; jt++) {
            int j = j0 + jt * 16 + lc;
            if (j >= 961) continue;
#pragma unroll
            for (int r = 0; r < 4; r++) {
                float g = bf2f(gb[(size_t)(mb + r) * 992 + j]);
                ob[(size_t)(mb + r) * 961 + j] = acc[mt][jt][r] + g;
            }
        }
    }
}

// =====================================================================
extern "C" void kernel_launch(void* const* d_in, const int* in_sizes, int n_in,
                              void* d_out, int out_size, void* d_ws, size_t ws_size,
                              hipStream_t stream)
{
    const float* zf      = (const float*)d_in[0];
    const float* xf      = (const float*)d_in[1];
    const float* Wq      = (const float*)d_in[2];
    const float* bq      = (const float*)d_in[3];
    const float* Ws      = (const float*)d_in[4];
    const float* bs      = (const float*)d_in[5];
    const float* Wg      = (const float*)d_in[6];
    const float* bg      = (const float*)d_in[7];
    const float* g_gamma = (const float*)d_in[8];
    const float* g_beta  = (const float*)d_in[9];
    const float* g_mean  = (const float*)d_in[10];
    const float* g_var   = (const float*)d_in[11];
    const float* Wfi     = (const float*)d_in[12];
    const float* bfi     = (const float*)d_in[13];
    const float* fi_gamma= (const float*)d_in[14];
    const float* fi_beta = (const float*)d_in[15];
    const float* fi_mean = (const float*)d_in[16];
    const float* fi_var  = (const float*)d_in[17];
    const float* Wm      = (const float*)d_in[18];
    const float* bm      = (const float*)d_in[19];
    const float* m_gamma = (const float*)d_in[20];
    const float* m_beta  = (const float*)d_in[21];
    const float* m_mean  = (const float*)d_in[22];
    const float* m_var   = (const float*)d_in[23];
    const float* prelu_a = (const float*)d_in[24];
    float* out = (float*)d_out;

    ushort_t* ws = (ushort_t*)d_ws;
    ushort_t* Wq_h  = ws + 0;         ushort_t* Wq_l  = ws + 65536;
    ushort_t* Ws_h  = ws + 131072;    ushort_t* Ws_l  = ws + 196608;
    ushort_t* Wg_h  = ws + 262144;    ushort_t* Wg_l  = ws + 327680;
    ushort_t* Wfi_h = ws + 393216;    ushort_t* Wfi_l = ws + 524288;
    ushort_t* wm_h  = ws + 655360;    ushort_t* wm_l  = ws + 802816;
    ushort_t* XT_h    = ws + 950272;      // 8,126,464 each
    ushort_t* XT_l    = ws + 9076736;
    ushort_t* xf_tT_h = ws + 17203200;
    ushort_t* xf_tT_l = ws + 25329664;
    ushort_t* zf_tT_h = ws + 33456128;    // 524,288 each
    ushort_t* zf_tT_l = ws + 33980416;
    ushort_t* zf_gT_h = ws + 34504704;
    ushort_t* zf_gT_l = ws + 35028992;
    ushort_t* xf_gT_h = ws + 35553280;
    ushort_t* xf_gT_l = ws + 43679744;
    ushort_t* gat_nf  = ws + 51806208;    // 8,126,464
    ushort_t* eT_h    = ws + 59932672;    // 2,097,152 each
    ushort_t* eT_l    = ws + 62029824;
    ushort_t* PT      = ws + 64126976;    // 32,505,856
    // gx lives INSIDE the PT region: written by attnfi, consumed by conv3x3,
    // then hspa overwrites the region with PT (strictly later in the stream).
    ushort_t* gxT_h   = ws + 64126976;    // 8,921,088
    ushort_t* gxT_l   = ws + 73048064;    // 8,921,088
    ushort_t* zfT_h   = ws + 96632832;    // 524,288 each
    ushort_t* zfT_l   = ws + 97157120;
    float* scsh       = (float*)(ws + 97681408);   // 2176 floats
    ushort_t* zgC_h   = ws + 97685760;    // 524,288 each
    ushort_t* zgC_l   = ws + 98210048;

    const float* sc_fi = scsh + 1536, *sh_fi = scsh + 1792;
    const float* sc_m  = scsh + 2048, *sh_m  = scsh + 2112;

    prep_all_kernel<<<1857, 256, 0, stream>>>(
        Wq, Ws, Wg, Wfi, Wm,
        bq, bs, bg, g_gamma, g_beta, g_mean, g_var,
        bfi, fi_gamma, fi_beta, fi_mean, fi_var,
        bm, m_gamma, m_beta, m_mean, m_var,
        Wq_h, Wq_l, Ws_h, Ws_l, Wg_h, Wg_l, Wfi_h, Wfi_l, wm_h, wm_l, scsh);

    // merged transposes: x<31 -> xf, else zf
    transpose_in_kernel<<<dim3(33, 8, 32), 256, 0, stream>>>(
        xf, XT_h, XT_l, zf, zfT_h, zfT_l);

    // merged fused-halves dualconv (32-row tiles): y<31 -> xf job, else zf job
    dualconv_mfma_kernel<<<dim3(32, 33), 256, 0, stream>>>(
        XT_h, XT_l, zfT_h, zfT_l,
        Wq_h, Wq_l, Ws_h, Ws_l, Wg_h, Wg_l, scsh,
        xf_tT_h, xf_tT_l, xf_gT_h, xf_gT_l,
        zf_tT_h, zf_tT_l, zf_gT_h, zf_gT_l,
        zgC_h, zgC_l);

    halo_zero_kernel<<<16, 256, 0, stream>>>(gxT_h, gxT_l);

    attnfi_mfma_kernel<<<dim3(32, 31), 256, 0, stream>>>(
        xf_tT_h, xf_tT_l, zf_tT_h, zf_tT_l, zgC_h, zgC_l,
        xf_gT_h, xf_gT_l, Wfi_h, Wfi_l, sc_fi, sh_fi,
        gxT_h, gxT_l, gat_nf);

    conv3x3_mfma_kernel<<<dim3(32, 16), 256, 0, stream>>>(
        gxT_h, gxT_l, wm_h, wm_l, sc_m, sh_m, prelu_a, eT_h, eT_l);

    hspa_mfma_kernel<<<dim3(32, 31), 512, 0, stream>>>(eT_h, eT_l, PT);

    out_mfma_kernel<<<dim3(32, 16), 256, 0, stream>>>(gat_nf, PT, out);
}